// Round 3
// baseline (499.107 us; speedup 1.0000x reference)
//
#include <hip/hip_runtime.h>
#include <math.h>

#define Nn 10000
#define Ee 320000
#define EE 330000      // E + N self loops
#define INF_ 256
#define HID 128
#define OUTC 128
#define NH 4
#define F1 512         // NH*HID
#define F2 512         // NH*OUTC
#define SLOPE 0.2f
#define NB 40          // ceil(Nn/256)

static __device__ __forceinline__ float lrelu(float x) { return fmaxf(x, SLOPE * x); }

// ---------------- CSR build ----------------
__global__ void init_counts(int* counts) {
    int i = blockIdx.x * 256 + threadIdx.x;
    if (i < Nn) counts[i] = 1;  // self loop
}

__global__ void count_edges(const int* __restrict__ ei, int* counts) {
    int e = blockIdx.x * 256 + threadIdx.x;
    if (e < Ee) atomicAdd(&counts[ei[Ee + e]], 1);
}

__global__ __launch_bounds__(256) void reduce_counts(const int* __restrict__ counts,
                                                     int* __restrict__ blocksums) {
    __shared__ int sd[256];
    int t = threadIdx.x, i = blockIdx.x * 256 + t;
    sd[t] = (i < Nn) ? counts[i] : 0;
    __syncthreads();
    for (int off = 128; off > 0; off >>= 1) {
        if (t < off) sd[t] += sd[t + off];
        __syncthreads();
    }
    if (t == 0) blocksums[blockIdx.x] = sd[0];
}

__global__ __launch_bounds__(64) void scan_sums(int* blocksums) {
    int t = threadIdx.x;
    int orig = (t < NB) ? blocksums[t] : 0;
    int v = orig;
    for (int off = 1; off < 64; off <<= 1) {
        int u = __shfl_up(v, off);
        if (t >= off) v += u;
    }
    if (t < NB) blocksums[t] = v - orig;  // exclusive
}

__global__ __launch_bounds__(256) void scan_final(const int* __restrict__ counts,
                                                  const int* __restrict__ blocksums,
                                                  int* __restrict__ offsets,
                                                  int* __restrict__ cursor) {
    __shared__ int sd[256];
    int t = threadIdx.x, i = blockIdx.x * 256 + t;
    int v = (i < Nn) ? counts[i] : 0;
    sd[t] = v;
    __syncthreads();
    int x = v;
    for (int off = 1; off < 256; off <<= 1) {
        int u = (t >= off) ? sd[t - off] : 0;
        __syncthreads();
        x += u;
        sd[t] = x;
        __syncthreads();
    }
    int base = blocksums[blockIdx.x];
    int e = base + x - v;  // exclusive
    if (i < Nn) {
        offsets[i] = e;
        cursor[i] = e;
        if (i == Nn - 1) offsets[Nn] = e + v;
    }
}

__global__ void scatter_edges(const int* __restrict__ ei, int* cursor, int* __restrict__ csr) {
    int t = blockIdx.x * 256 + threadIdx.x;
    if (t >= EE) return;
    int src, dst;
    if (t < Ee) { src = ei[t]; dst = ei[Ee + t]; }
    else        { src = t - Ee; dst = t - Ee; }
    int pos = atomicAdd(&cursor[dst], 1);
    csr[pos] = src;
}

// ---------------- fp32 tiled GEMM (64x64x16, 4x4 per thread, padded LDS) ----------------
__global__ __launch_bounds__(256) void gemm64(const float* __restrict__ A,
                                              const float* __restrict__ B,
                                              float* __restrict__ C,
                                              int M, int N, int K) {
    __shared__ float As[16][72];
    __shared__ float Bs[16][72];
    const int tid = threadIdx.x;
    const int bm = blockIdx.x * 64, bn = blockIdx.y * 64;
    const int tx = tid & 15, ty = tid >> 4;
    const int arow = tid >> 2, acol = (tid & 3) << 2;
    const int brow = tid >> 4, bcol = (tid & 15) << 2;
    float acc[4][4] = {};
    for (int k0 = 0; k0 < K; k0 += 16) {
        float4 av;
        int gm = bm + arow;
        if (gm < M) av = *(const float4*)(A + (size_t)gm * K + k0 + acol);
        else av = make_float4(0.f, 0.f, 0.f, 0.f);
        As[acol + 0][arow] = av.x;
        As[acol + 1][arow] = av.y;
        As[acol + 2][arow] = av.z;
        As[acol + 3][arow] = av.w;
        *(float4*)&Bs[brow][bcol] = *(const float4*)(B + (size_t)(k0 + brow) * N + bn + bcol);
        __syncthreads();
#pragma unroll
        for (int k = 0; k < 16; k++) {
            float4 a = *(const float4*)&As[k][ty << 2];
            float4 b = *(const float4*)&Bs[k][tx << 2];
            float ar[4] = {a.x, a.y, a.z, a.w};
            float br[4] = {b.x, b.y, b.z, b.w};
#pragma unroll
            for (int i = 0; i < 4; i++)
#pragma unroll
                for (int j = 0; j < 4; j++) acc[i][j] += ar[i] * br[j];
        }
        __syncthreads();
    }
#pragma unroll
    for (int i = 0; i < 4; i++) {
        int gm = bm + (ty << 2) + i;
        if (gm < M) {
            float4 o = make_float4(acc[i][0], acc[i][1], acc[i][2], acc[i][3]);
            *(float4*)(C + (size_t)gm * N + bn + (tx << 2)) = o;
        }
    }
}

// ---------------- alpha_s / alpha_d per (node, head) ----------------
__global__ __launch_bounds__(256) void alphas_kernel(const float* __restrict__ h,
                                                     const float* __restrict__ a_src,
                                                     const float* __restrict__ a_dst,
                                                     float* __restrict__ as_out,
                                                     float* __restrict__ ad_out) {
    int n = blockIdx.x;
    int head = threadIdx.x >> 6;
    int lane = threadIdx.x & 63;
    const float* hp = h + (size_t)n * F1 + head * 128 + lane * 2;
    const float* sp = a_src + head * 128 + lane * 2;
    const float* dp = a_dst + head * 128 + lane * 2;
    float2 hv = *(const float2*)hp;
    float2 sv = *(const float2*)sp;
    float2 dv = *(const float2*)dp;
    float s = hv.x * sv.x + hv.y * sv.y;
    float d = hv.x * dv.x + hv.y * dv.y;
    for (int off = 32; off > 0; off >>= 1) {
        s += __shfl_xor(s, off);
        d += __shfl_xor(d, off);
    }
    if (lane == 0) {
        as_out[n * NH + head] = s;
        ad_out[n * NH + head] = d;
    }
}

// ---------------- softmax pass A (wedge stored [head][edge]) ----------------
__global__ __launch_bounds__(256) void passA(const int* __restrict__ offsets,
                                             const int* __restrict__ csr,
                                             const float* __restrict__ as,
                                             const float* __restrict__ ad,
                                             float* __restrict__ wedgeh,
                                             float* __restrict__ invd) {
    int n = blockIdx.x * 4 + (threadIdx.x >> 6);
    int lane = threadIdx.x & 63;
    int start = offsets[n], end = offsets[n + 1];
    float4 adv = *(const float4*)&ad[n * NH];
    float m0 = -1e30f, m1 = -1e30f, m2 = -1e30f, m3 = -1e30f;
    for (int idx = start + lane; idx < end; idx += 64) {
        int src = csr[idx];
        float4 asv = *(const float4*)&as[src * NH];
        m0 = fmaxf(m0, lrelu(asv.x + adv.x));
        m1 = fmaxf(m1, lrelu(asv.y + adv.y));
        m2 = fmaxf(m2, lrelu(asv.z + adv.z));
        m3 = fmaxf(m3, lrelu(asv.w + adv.w));
    }
    for (int off = 32; off > 0; off >>= 1) {
        m0 = fmaxf(m0, __shfl_xor(m0, off));
        m1 = fmaxf(m1, __shfl_xor(m1, off));
        m2 = fmaxf(m2, __shfl_xor(m2, off));
        m3 = fmaxf(m3, __shfl_xor(m3, off));
    }
    float s0 = 0.f, s1 = 0.f, s2 = 0.f, s3 = 0.f;
    for (int idx = start + lane; idx < end; idx += 64) {
        int src = csr[idx];
        float4 asv = *(const float4*)&as[src * NH];
        float e0 = __expf(lrelu(asv.x + adv.x) - m0);
        float e1 = __expf(lrelu(asv.y + adv.y) - m1);
        float e2 = __expf(lrelu(asv.z + adv.z) - m2);
        float e3 = __expf(lrelu(asv.w + adv.w) - m3);
        wedgeh[idx] = e0;
        wedgeh[EE + idx] = e1;
        wedgeh[2 * EE + idx] = e2;
        wedgeh[3 * EE + idx] = e3;
        s0 += e0; s1 += e1; s2 += e2; s3 += e3;
    }
    for (int off = 32; off > 0; off >>= 1) {
        s0 += __shfl_xor(s0, off);
        s1 += __shfl_xor(s1, off);
        s2 += __shfl_xor(s2, off);
        s3 += __shfl_xor(s3, off);
    }
    if (lane == 0) {
        *(float4*)&invd[n * NH] = make_float4(1.f / (s0 + 1e-16f), 1.f / (s1 + 1e-16f),
                                              1.f / (s2 + 1e-16f), 1.f / (s3 + 1e-16f));
    }
}

// ---------------- pass B layer 1: XCD-sliced (slice = blockIdx & 7) ----------------
// 8 slices of 64 channels; per-XCD slice working set = 2.56 MB -> L2-resident.
// 256 thr = 4 waves = 4 nodes per block; 1 channel per lane.
__global__ __launch_bounds__(256) void passB1s(const int* __restrict__ offsets,
                                               const int* __restrict__ csr,
                                               const float* __restrict__ wedgeh,
                                               const float* __restrict__ invd,
                                               const float* __restrict__ h1,
                                               const float* __restrict__ b1,
                                               float* __restrict__ agg) {
    int slice = blockIdx.x & 7;
    int n = (blockIdx.x >> 3) * 4 + (threadIdx.x >> 6);
    int lane = threadIdx.x & 63;
    int head = slice >> 1;
    int c = slice * 64 + lane;
    int start = offsets[n], end = offsets[n + 1];
    float inv = invd[n * NH + head];
    const int* cp = csr;
    const float* wh = wedgeh + (size_t)head * EE;
    float acc = 0.f;
    int idx = start;
    for (; idx + 3 < end; idx += 4) {
        int s0 = __builtin_nontemporal_load(&cp[idx]);
        int s1 = __builtin_nontemporal_load(&cp[idx + 1]);
        int s2 = __builtin_nontemporal_load(&cp[idx + 2]);
        int s3 = __builtin_nontemporal_load(&cp[idx + 3]);
        float w0 = __builtin_nontemporal_load(&wh[idx]);
        float w1 = __builtin_nontemporal_load(&wh[idx + 1]);
        float w2 = __builtin_nontemporal_load(&wh[idx + 2]);
        float w3 = __builtin_nontemporal_load(&wh[idx + 3]);
        acc += h1[(size_t)s0 * F1 + c] * w0 + h1[(size_t)s1 * F1 + c] * w1 +
               h1[(size_t)s2 * F1 + c] * w2 + h1[(size_t)s3 * F1 + c] * w3;
    }
    for (; idx < end; ++idx) {
        int s0 = __builtin_nontemporal_load(&cp[idx]);
        float w0 = __builtin_nontemporal_load(&wh[idx]);
        acc += h1[(size_t)s0 * F1 + c] * w0;
    }
    agg[(size_t)n * F1 + c] = fmaxf(acc * inv + b1[c], 0.f);
}

// ---------------- init d_out with bias ----------------
__global__ void init_out(const float* __restrict__ b2, float* __restrict__ out) {
    int i = blockIdx.x * 256 + threadIdx.x;
    if (i < Nn * OUTC) out[i] = b2[i & (OUTC - 1)];
}

// ---------------- pass B layer 2: XCD-sliced + atomic head-mean into d_out ----------------
__global__ __launch_bounds__(256) void passB2s(const int* __restrict__ offsets,
                                               const int* __restrict__ csr,
                                               const float* __restrict__ wedgeh,
                                               const float* __restrict__ invd,
                                               const float* __restrict__ h2,
                                               float* __restrict__ out) {
    int slice = blockIdx.x & 7;
    int n = (blockIdx.x >> 3) * 4 + (threadIdx.x >> 6);
    int lane = threadIdx.x & 63;
    int head = slice >> 1;
    int c = slice * 64 + lane;             // channel in h2 row
    int oc = (slice & 1) * 64 + lane;      // output channel
    int start = offsets[n], end = offsets[n + 1];
    float inv = invd[n * NH + head];
    const int* cp = csr;
    const float* wh = wedgeh + (size_t)head * EE;
    float acc = 0.f;
    int idx = start;
    for (; idx + 3 < end; idx += 4) {
        int s0 = __builtin_nontemporal_load(&cp[idx]);
        int s1 = __builtin_nontemporal_load(&cp[idx + 1]);
        int s2 = __builtin_nontemporal_load(&cp[idx + 2]);
        int s3 = __builtin_nontemporal_load(&cp[idx + 3]);
        float w0 = __builtin_nontemporal_load(&wh[idx]);
        float w1 = __builtin_nontemporal_load(&wh[idx + 1]);
        float w2 = __builtin_nontemporal_load(&wh[idx + 2]);
        float w3 = __builtin_nontemporal_load(&wh[idx + 3]);
        acc += h2[(size_t)s0 * F2 + c] * w0 + h2[(size_t)s1 * F2 + c] * w1 +
               h2[(size_t)s2 * F2 + c] * w2 + h2[(size_t)s3 * F2 + c] * w3;
    }
    for (; idx < end; ++idx) {
        int s0 = __builtin_nontemporal_load(&cp[idx]);
        float w0 = __builtin_nontemporal_load(&wh[idx]);
        acc += h2[(size_t)s0 * F2 + c] * w0;
    }
    atomicAdd(&out[(size_t)n * OUTC + oc], 0.25f * acc * inv);
}

extern "C" void kernel_launch(void* const* d_in, const int* in_sizes, int n_in,
                              void* d_out, int out_size, void* d_ws, size_t ws_size,
                              hipStream_t stream) {
    const float* x      = (const float*)d_in[0];
    const int*   ei     = (const int*)d_in[1];
    const float* W1     = (const float*)d_in[2];
    const float* a_src1 = (const float*)d_in[3];
    const float* a_dst1 = (const float*)d_in[4];
    const float* b1     = (const float*)d_in[5];
    const float* W2     = (const float*)d_in[6];
    const float* a_src2 = (const float*)d_in[7];
    const float* a_dst2 = (const float*)d_in[8];
    const float* b2     = (const float*)d_in[9];
    float* out = (float*)d_out;

    const size_t NF = (size_t)Nn * F1;
    float* f = (float*)d_ws;
    float* h1    = f;
    float* h2    = h1 + NF;
    float* agg1  = h2 + NF;
    float* as1   = agg1 + NF;
    float* ad1   = as1 + Nn * NH;
    float* as2   = ad1 + Nn * NH;
    float* ad2   = as2 + Nn * NH;
    float* invd1 = ad2 + Nn * NH;
    float* invd2 = invd1 + Nn * NH;
    float* wedgeh = invd2 + Nn * NH;    // NH*EE floats, [head][edge]
    int* counts    = (int*)(wedgeh + (size_t)EE * NH);
    int* offsets   = counts + Nn;
    int* cursor    = offsets + Nn + 1;
    int* csr       = cursor + Nn;
    int* blocksums = csr + EE;

    // CSR build
    init_counts<<<(Nn + 255) / 256, 256, 0, stream>>>(counts);
    count_edges<<<(Ee + 255) / 256, 256, 0, stream>>>(ei, counts);
    reduce_counts<<<NB, 256, 0, stream>>>(counts, blocksums);
    scan_sums<<<1, 64, 0, stream>>>(blocksums);
    scan_final<<<NB, 256, 0, stream>>>(counts, blocksums, offsets, cursor);
    scatter_edges<<<(EE + 255) / 256, 256, 0, stream>>>(ei, cursor, csr);

    // Layer 1
    gemm64<<<dim3((Nn + 63) / 64, F1 / 64), 256, 0, stream>>>(x, W1, h1, Nn, F1, INF_);
    alphas_kernel<<<Nn, 256, 0, stream>>>(h1, a_src1, a_dst1, as1, ad1);
    passA<<<Nn / 4, 256, 0, stream>>>(offsets, csr, as1, ad1, wedgeh, invd1);
    passB1s<<<(Nn / 4) * 8, 256, 0, stream>>>(offsets, csr, wedgeh, invd1, h1, b1, agg1);

    // Layer 2
    gemm64<<<dim3((Nn + 63) / 64, F2 / 64), 256, 0, stream>>>(agg1, W2, h2, Nn, F2, F1);
    alphas_kernel<<<Nn, 256, 0, stream>>>(h2, a_src2, a_dst2, as2, ad2);
    passA<<<Nn / 4, 256, 0, stream>>>(offsets, csr, as2, ad2, wedgeh, invd2);
    init_out<<<(Nn * OUTC + 255) / 256, 256, 0, stream>>>(b2, out);
    passB2s<<<(Nn / 4) * 8, 256, 0, stream>>>(offsets, csr, wedgeh, invd2, h2, out);
}

// Round 4
// 423.009 us; speedup vs baseline: 1.1799x; 1.1799x over previous
//
#include <hip/hip_runtime.h>
#include <math.h>

#define Nn 10000
#define Ee 320000
#define EE 330000      // E + N self loops
#define INF_ 256
#define HID 128
#define OUTC 128
#define NH 4
#define F1 512         // NH*HID
#define F2 512         // NH*OUTC
#define SLOPE 0.2f
#define NB 40          // ceil(Nn/256)

static __device__ __forceinline__ float lrelu(float x) { return fmaxf(x, SLOPE * x); }

// ---------------- CSR build ----------------
__global__ void init_counts(int* counts) {
    int i = blockIdx.x * 256 + threadIdx.x;
    if (i < Nn) counts[i] = 1;  // self loop
}

__global__ void count_edges(const int* __restrict__ ei, int* counts) {
    int e = blockIdx.x * 256 + threadIdx.x;
    if (e < Ee) atomicAdd(&counts[ei[Ee + e]], 1);
}

__global__ __launch_bounds__(256) void reduce_counts(const int* __restrict__ counts,
                                                     int* __restrict__ blocksums) {
    __shared__ int sd[256];
    int t = threadIdx.x, i = blockIdx.x * 256 + t;
    sd[t] = (i < Nn) ? counts[i] : 0;
    __syncthreads();
    for (int off = 128; off > 0; off >>= 1) {
        if (t < off) sd[t] += sd[t + off];
        __syncthreads();
    }
    if (t == 0) blocksums[blockIdx.x] = sd[0];
}

__global__ __launch_bounds__(64) void scan_sums(int* blocksums) {
    int t = threadIdx.x;
    int orig = (t < NB) ? blocksums[t] : 0;
    int v = orig;
    for (int off = 1; off < 64; off <<= 1) {
        int u = __shfl_up(v, off);
        if (t >= off) v += u;
    }
    if (t < NB) blocksums[t] = v - orig;  // exclusive
}

__global__ __launch_bounds__(256) void scan_final(const int* __restrict__ counts,
                                                  const int* __restrict__ blocksums,
                                                  int* __restrict__ offsets,
                                                  int* __restrict__ cursor) {
    __shared__ int sd[256];
    int t = threadIdx.x, i = blockIdx.x * 256 + t;
    int v = (i < Nn) ? counts[i] : 0;
    sd[t] = v;
    __syncthreads();
    int x = v;
    for (int off = 1; off < 256; off <<= 1) {
        int u = (t >= off) ? sd[t - off] : 0;
        __syncthreads();
        x += u;
        sd[t] = x;
        __syncthreads();
    }
    int base = blocksums[blockIdx.x];
    int e = base + x - v;  // exclusive
    if (i < Nn) {
        offsets[i] = e;
        cursor[i] = e;
        if (i == Nn - 1) offsets[Nn] = e + v;
    }
}

__global__ void scatter_edges(const int* __restrict__ ei, int* cursor, int* __restrict__ csr) {
    int t = blockIdx.x * 256 + threadIdx.x;
    if (t >= EE) return;
    int src, dst;
    if (t < Ee) { src = ei[t]; dst = ei[Ee + t]; }
    else        { src = t - Ee; dst = t - Ee; }
    int pos = atomicAdd(&cursor[dst], 1);
    csr[pos] = src;
}

// ---------------- fp32 tiled GEMM (64x64x16, 4x4 per thread, padded LDS) ----------------
__global__ __launch_bounds__(256) void gemm64(const float* __restrict__ A,
                                              const float* __restrict__ B,
                                              float* __restrict__ C,
                                              int M, int N, int K) {
    __shared__ float As[16][72];
    __shared__ float Bs[16][72];
    const int tid = threadIdx.x;
    const int bm = blockIdx.x * 64, bn = blockIdx.y * 64;
    const int tx = tid & 15, ty = tid >> 4;
    const int arow = tid >> 2, acol = (tid & 3) << 2;
    const int brow = tid >> 4, bcol = (tid & 15) << 2;
    float acc[4][4] = {};
    for (int k0 = 0; k0 < K; k0 += 16) {
        float4 av;
        int gm = bm + arow;
        if (gm < M) av = *(const float4*)(A + (size_t)gm * K + k0 + acol);
        else av = make_float4(0.f, 0.f, 0.f, 0.f);
        As[acol + 0][arow] = av.x;
        As[acol + 1][arow] = av.y;
        As[acol + 2][arow] = av.z;
        As[acol + 3][arow] = av.w;
        *(float4*)&Bs[brow][bcol] = *(const float4*)(B + (size_t)(k0 + brow) * N + bn + bcol);
        __syncthreads();
#pragma unroll
        for (int k = 0; k < 16; k++) {
            float4 a = *(const float4*)&As[k][ty << 2];
            float4 b = *(const float4*)&Bs[k][tx << 2];
            float ar[4] = {a.x, a.y, a.z, a.w};
            float br[4] = {b.x, b.y, b.z, b.w};
#pragma unroll
            for (int i = 0; i < 4; i++)
#pragma unroll
                for (int j = 0; j < 4; j++) acc[i][j] += ar[i] * br[j];
        }
        __syncthreads();
    }
#pragma unroll
    for (int i = 0; i < 4; i++) {
        int gm = bm + (ty << 2) + i;
        if (gm < M) {
            float4 o = make_float4(acc[i][0], acc[i][1], acc[i][2], acc[i][3]);
            *(float4*)(C + (size_t)gm * N + bn + (tx << 2)) = o;
        }
    }
}

// ---------------- alpha_s / alpha_d per (node, head) ----------------
__global__ __launch_bounds__(256) void alphas_kernel(const float* __restrict__ h,
                                                     const float* __restrict__ a_src,
                                                     const float* __restrict__ a_dst,
                                                     float* __restrict__ as_out,
                                                     float* __restrict__ ad_out) {
    int n = blockIdx.x;
    int head = threadIdx.x >> 6;
    int lane = threadIdx.x & 63;
    const float* hp = h + (size_t)n * F1 + head * 128 + lane * 2;
    const float* sp = a_src + head * 128 + lane * 2;
    const float* dp = a_dst + head * 128 + lane * 2;
    float2 hv = *(const float2*)hp;
    float2 sv = *(const float2*)sp;
    float2 dv = *(const float2*)dp;
    float s = hv.x * sv.x + hv.y * sv.y;
    float d = hv.x * dv.x + hv.y * dv.y;
    for (int off = 32; off > 0; off >>= 1) {
        s += __shfl_xor(s, off);
        d += __shfl_xor(d, off);
    }
    if (lane == 0) {
        as_out[n * NH + head] = s;
        ad_out[n * NH + head] = d;
    }
}

// ---------------- softmax pass A: writes packed (src, w) per head ----------------
__global__ __launch_bounds__(256) void passA(const int* __restrict__ offsets,
                                             const int* __restrict__ csr,
                                             const float* __restrict__ as,
                                             const float* __restrict__ ad,
                                             float2* __restrict__ epk,
                                             float* __restrict__ invd) {
    int n = blockIdx.x * 4 + (threadIdx.x >> 6);
    int lane = threadIdx.x & 63;
    int start = offsets[n], end = offsets[n + 1];
    float4 adv = *(const float4*)&ad[n * NH];
    float m0 = -1e30f, m1 = -1e30f, m2 = -1e30f, m3 = -1e30f;
    for (int idx = start + lane; idx < end; idx += 64) {
        int src = csr[idx];
        float4 asv = *(const float4*)&as[src * NH];
        m0 = fmaxf(m0, lrelu(asv.x + adv.x));
        m1 = fmaxf(m1, lrelu(asv.y + adv.y));
        m2 = fmaxf(m2, lrelu(asv.z + adv.z));
        m3 = fmaxf(m3, lrelu(asv.w + adv.w));
    }
    for (int off = 32; off > 0; off >>= 1) {
        m0 = fmaxf(m0, __shfl_xor(m0, off));
        m1 = fmaxf(m1, __shfl_xor(m1, off));
        m2 = fmaxf(m2, __shfl_xor(m2, off));
        m3 = fmaxf(m3, __shfl_xor(m3, off));
    }
    float s0 = 0.f, s1 = 0.f, s2 = 0.f, s3 = 0.f;
    for (int idx = start + lane; idx < end; idx += 64) {
        int src = csr[idx];
        float4 asv = *(const float4*)&as[src * NH];
        float e0 = __expf(lrelu(asv.x + adv.x) - m0);
        float e1 = __expf(lrelu(asv.y + adv.y) - m1);
        float e2 = __expf(lrelu(asv.z + adv.z) - m2);
        float e3 = __expf(lrelu(asv.w + adv.w) - m3);
        float fs = __int_as_float(src);
        epk[idx] = make_float2(fs, e0);
        epk[EE + idx] = make_float2(fs, e1);
        epk[2 * EE + idx] = make_float2(fs, e2);
        epk[3 * EE + idx] = make_float2(fs, e3);
        s0 += e0; s1 += e1; s2 += e2; s3 += e3;
    }
    for (int off = 32; off > 0; off >>= 1) {
        s0 += __shfl_xor(s0, off);
        s1 += __shfl_xor(s1, off);
        s2 += __shfl_xor(s2, off);
        s3 += __shfl_xor(s3, off);
    }
    if (lane == 0) {
        *(float4*)&invd[n * NH] = make_float4(1.f / (s0 + 1e-16f), 1.f / (s1 + 1e-16f),
                                              1.f / (s2 + 1e-16f), 1.f / (s3 + 1e-16f));
    }
}

// ---------------- pass B layer 1: XCD-sliced, quarter-wave float4 ----------------
// slice = blockIdx&7 -> XCD; 64 channels/slice (2.56 MB, L2-resident).
// Wave: eg = lane>>4 covers 4 edges in parallel, cg = lane&15 covers 64 ch as float4.
__global__ __launch_bounds__(256) void passB1q(const int* __restrict__ offsets,
                                               const float2* __restrict__ epk,
                                               const float* __restrict__ invd,
                                               const float* __restrict__ h1,
                                               const float* __restrict__ b1,
                                               float* __restrict__ agg) {
    int slice = blockIdx.x & 7;
    int n = (blockIdx.x >> 3) * 4 + (threadIdx.x >> 6);
    int lane = threadIdx.x & 63;
    int eg = lane >> 4, cg = lane & 15;
    int head = slice >> 1;
    int c = slice * 64 + (cg << 2);
    int start = offsets[n], end = offsets[n + 1];
    float inv = invd[n * NH + head];
    const float2* ep = epk + (size_t)head * EE;
    float4 acc = make_float4(0.f, 0.f, 0.f, 0.f);
    int idx = start + eg;
    float2 p = (idx < end) ? ep[idx] : make_float2(0.f, 0.f);
    while (idx < end) {
        int nidx = idx + 4;
        float2 pn = (nidx < end) ? ep[nidx] : make_float2(0.f, 0.f);
        int s = __float_as_int(p.x);
        float w = p.y;
        float4 v = *(const float4*)&h1[(size_t)s * F1 + c];
        acc.x += v.x * w; acc.y += v.y * w; acc.z += v.z * w; acc.w += v.w * w;
        idx = nidx; p = pn;
    }
    acc.x += __shfl_xor(acc.x, 16); acc.y += __shfl_xor(acc.y, 16);
    acc.z += __shfl_xor(acc.z, 16); acc.w += __shfl_xor(acc.w, 16);
    acc.x += __shfl_xor(acc.x, 32); acc.y += __shfl_xor(acc.y, 32);
    acc.z += __shfl_xor(acc.z, 32); acc.w += __shfl_xor(acc.w, 32);
    if (eg == 0) {
        float4 bv = *(const float4*)&b1[c];
        float4 o;
        o.x = fmaxf(acc.x * inv + bv.x, 0.f);
        o.y = fmaxf(acc.y * inv + bv.y, 0.f);
        o.z = fmaxf(acc.z * inv + bv.z, 0.f);
        o.w = fmaxf(acc.w * inv + bv.w, 0.f);
        *(float4*)&agg[(size_t)n * F1 + c] = o;
    }
}

// ---------------- init d_out with bias ----------------
__global__ void init_out(const float* __restrict__ b2, float* __restrict__ out) {
    int i = blockIdx.x * 256 + threadIdx.x;
    if (i < Nn * OUTC) out[i] = b2[i & (OUTC - 1)];
}

// ---------------- pass B layer 2: quarter-wave + atomic head-mean ----------------
__global__ __launch_bounds__(256) void passB2q(const int* __restrict__ offsets,
                                               const float2* __restrict__ epk,
                                               const float* __restrict__ invd,
                                               const float* __restrict__ h2,
                                               float* __restrict__ out) {
    int slice = blockIdx.x & 7;
    int n = (blockIdx.x >> 3) * 4 + (threadIdx.x >> 6);
    int lane = threadIdx.x & 63;
    int eg = lane >> 4, cg = lane & 15;
    int head = slice >> 1;
    int c = slice * 64 + (cg << 2);
    int start = offsets[n], end = offsets[n + 1];
    float inv = invd[n * NH + head];
    const float2* ep = epk + (size_t)head * EE;
    float4 acc = make_float4(0.f, 0.f, 0.f, 0.f);
    int idx = start + eg;
    float2 p = (idx < end) ? ep[idx] : make_float2(0.f, 0.f);
    while (idx < end) {
        int nidx = idx + 4;
        float2 pn = (nidx < end) ? ep[nidx] : make_float2(0.f, 0.f);
        int s = __float_as_int(p.x);
        float w = p.y;
        float4 v = *(const float4*)&h2[(size_t)s * F2 + c];
        acc.x += v.x * w; acc.y += v.y * w; acc.z += v.z * w; acc.w += v.w * w;
        idx = nidx; p = pn;
    }
    acc.x += __shfl_xor(acc.x, 16); acc.y += __shfl_xor(acc.y, 16);
    acc.z += __shfl_xor(acc.z, 16); acc.w += __shfl_xor(acc.w, 16);
    acc.x += __shfl_xor(acc.x, 32); acc.y += __shfl_xor(acc.y, 32);
    acc.z += __shfl_xor(acc.z, 32); acc.w += __shfl_xor(acc.w, 32);
    if (eg == 0) {
        int oc = (slice & 1) * 64 + (cg << 2);
        float* op = &out[(size_t)n * OUTC + oc];
        float q = 0.25f * inv;
        atomicAdd(op + 0, acc.x * q);
        atomicAdd(op + 1, acc.y * q);
        atomicAdd(op + 2, acc.z * q);
        atomicAdd(op + 3, acc.w * q);
    }
}

extern "C" void kernel_launch(void* const* d_in, const int* in_sizes, int n_in,
                              void* d_out, int out_size, void* d_ws, size_t ws_size,
                              hipStream_t stream) {
    const float* x      = (const float*)d_in[0];
    const int*   ei     = (const int*)d_in[1];
    const float* W1     = (const float*)d_in[2];
    const float* a_src1 = (const float*)d_in[3];
    const float* a_dst1 = (const float*)d_in[4];
    const float* b1     = (const float*)d_in[5];
    const float* W2     = (const float*)d_in[6];
    const float* a_src2 = (const float*)d_in[7];
    const float* a_dst2 = (const float*)d_in[8];
    const float* b2     = (const float*)d_in[9];
    float* out = (float*)d_out;

    const size_t NF = (size_t)Nn * F1;
    float* f = (float*)d_ws;
    float* h1    = f;                    // layer-1 features; reused as h2 (dead after passB1)
    float* h2    = h1;                   // alias — saves 20.5 MB of workspace
    float* agg1  = h1 + NF;
    float* as1   = agg1 + NF;
    float* ad1   = as1 + Nn * NH;
    float* as2   = ad1 + Nn * NH;
    float* ad2   = as2 + Nn * NH;
    float* invd1 = ad2 + Nn * NH;
    float* invd2 = invd1 + Nn * NH;
    float2* epk  = (float2*)(invd2 + Nn * NH);   // NH*EE float2, [head][edge] = (src,w)
    int* counts    = (int*)(epk + (size_t)NH * EE);
    int* offsets   = counts + Nn;
    int* cursor    = offsets + Nn + 1;
    int* csr       = cursor + Nn;
    int* blocksums = csr + EE;

    // CSR build
    init_counts<<<(Nn + 255) / 256, 256, 0, stream>>>(counts);
    count_edges<<<(Ee + 255) / 256, 256, 0, stream>>>(ei, counts);
    reduce_counts<<<NB, 256, 0, stream>>>(counts, blocksums);
    scan_sums<<<1, 64, 0, stream>>>(blocksums);
    scan_final<<<NB, 256, 0, stream>>>(counts, blocksums, offsets, cursor);
    scatter_edges<<<(EE + 255) / 256, 256, 0, stream>>>(ei, cursor, csr);

    // Layer 1
    gemm64<<<dim3((Nn + 63) / 64, F1 / 64), 256, 0, stream>>>(x, W1, h1, Nn, F1, INF_);
    alphas_kernel<<<Nn, 256, 0, stream>>>(h1, a_src1, a_dst1, as1, ad1);
    passA<<<Nn / 4, 256, 0, stream>>>(offsets, csr, as1, ad1, epk, invd1);
    passB1q<<<(Nn / 4) * 8, 256, 0, stream>>>(offsets, epk, invd1, h1, b1, agg1);

    // Layer 2
    gemm64<<<dim3((Nn + 63) / 64, F2 / 64), 256, 0, stream>>>(agg1, W2, h2, Nn, F2, F1);
    alphas_kernel<<<Nn, 256, 0, stream>>>(h2, a_src2, a_dst2, as2, ad2);
    passA<<<Nn / 4, 256, 0, stream>>>(offsets, csr, as2, ad2, epk, invd2);
    init_out<<<(Nn * OUTC + 255) / 256, 256, 0, stream>>>(b2, out);
    passB2q<<<(Nn / 4) * 8, 256, 0, stream>>>(offsets, epk, invd2, h2, out);
}

// Round 5
// 350.469 us; speedup vs baseline: 1.4241x; 1.2070x over previous
//
#include <hip/hip_runtime.h>
#include <hip/hip_fp16.h>
#include <math.h>

#define Nn 10000
#define Ee 320000
#define EE 330000      // E + N self loops
#define INF_ 256
#define HID 128
#define OUTC 128
#define NH 4
#define F1 512         // NH*HID
#define F2 512         // NH*OUTC
#define SLOPE 0.2f
#define NB 40          // ceil(Nn/256)

static __device__ __forceinline__ float lrelu(float x) { return fmaxf(x, SLOPE * x); }

// ---------------- CSR build ----------------
__global__ void init_counts(int* counts) {
    int i = blockIdx.x * 256 + threadIdx.x;
    if (i < Nn) counts[i] = 1;  // self loop
}

__global__ void count_edges(const int* __restrict__ ei, int* counts) {
    int e = blockIdx.x * 256 + threadIdx.x;
    if (e < Ee) atomicAdd(&counts[ei[Ee + e]], 1);
}

__global__ __launch_bounds__(256) void reduce_counts(const int* __restrict__ counts,
                                                     int* __restrict__ blocksums) {
    __shared__ int sd[256];
    int t = threadIdx.x, i = blockIdx.x * 256 + t;
    sd[t] = (i < Nn) ? counts[i] : 0;
    __syncthreads();
    for (int off = 128; off > 0; off >>= 1) {
        if (t < off) sd[t] += sd[t + off];
        __syncthreads();
    }
    if (t == 0) blocksums[blockIdx.x] = sd[0];
}

__global__ __launch_bounds__(64) void scan_sums(int* blocksums) {
    int t = threadIdx.x;
    int orig = (t < NB) ? blocksums[t] : 0;
    int v = orig;
    for (int off = 1; off < 64; off <<= 1) {
        int u = __shfl_up(v, off);
        if (t >= off) v += u;
    }
    if (t < NB) blocksums[t] = v - orig;  // exclusive
}

__global__ __launch_bounds__(256) void scan_final(const int* __restrict__ counts,
                                                  const int* __restrict__ blocksums,
                                                  int* __restrict__ offsets,
                                                  int* __restrict__ cursor) {
    __shared__ int sd[256];
    int t = threadIdx.x, i = blockIdx.x * 256 + t;
    int v = (i < Nn) ? counts[i] : 0;
    sd[t] = v;
    __syncthreads();
    int x = v;
    for (int off = 1; off < 256; off <<= 1) {
        int u = (t >= off) ? sd[t - off] : 0;
        __syncthreads();
        x += u;
        sd[t] = x;
        __syncthreads();
    }
    int base = blocksums[blockIdx.x];
    int e = base + x - v;  // exclusive
    if (i < Nn) {
        offsets[i] = e;
        cursor[i] = e;
        if (i == Nn - 1) offsets[Nn] = e + v;
    }
}

__global__ void scatter_edges(const int* __restrict__ ei, int* cursor, int* __restrict__ csr) {
    int t = blockIdx.x * 256 + threadIdx.x;
    if (t >= EE) return;
    int src, dst;
    if (t < Ee) { src = ei[t]; dst = ei[Ee + t]; }
    else        { src = t - Ee; dst = t - Ee; }
    int pos = atomicAdd(&cursor[dst], 1);
    csr[pos] = src;
}

// ---------------- fp32 tiled GEMM, fp16 output (64x64x16, 4x4/thr, padded LDS) ----------------
__global__ __launch_bounds__(256) void gemm_f16(const float* __restrict__ A,
                                                const float* __restrict__ B,
                                                __half* __restrict__ C,
                                                int M, int N, int K) {
    __shared__ float As[16][72];
    __shared__ float Bs[16][72];
    const int tid = threadIdx.x;
    const int bm = blockIdx.x * 64, bn = blockIdx.y * 64;
    const int tx = tid & 15, ty = tid >> 4;
    const int arow = tid >> 2, acol = (tid & 3) << 2;
    const int brow = tid >> 4, bcol = (tid & 15) << 2;
    float acc[4][4] = {};
    for (int k0 = 0; k0 < K; k0 += 16) {
        float4 av;
        int gm = bm + arow;
        if (gm < M) av = *(const float4*)(A + (size_t)gm * K + k0 + acol);
        else av = make_float4(0.f, 0.f, 0.f, 0.f);
        As[acol + 0][arow] = av.x;
        As[acol + 1][arow] = av.y;
        As[acol + 2][arow] = av.z;
        As[acol + 3][arow] = av.w;
        *(float4*)&Bs[brow][bcol] = *(const float4*)(B + (size_t)(k0 + brow) * N + bn + bcol);
        __syncthreads();
#pragma unroll
        for (int k = 0; k < 16; k++) {
            float4 a = *(const float4*)&As[k][ty << 2];
            float4 b = *(const float4*)&Bs[k][tx << 2];
            float ar[4] = {a.x, a.y, a.z, a.w};
            float br[4] = {b.x, b.y, b.z, b.w};
#pragma unroll
            for (int i = 0; i < 4; i++)
#pragma unroll
                for (int j = 0; j < 4; j++) acc[i][j] += ar[i] * br[j];
        }
        __syncthreads();
    }
#pragma unroll
    for (int i = 0; i < 4; i++) {
        int gm = bm + (ty << 2) + i;
        if (gm < M) {
            __half2 q[2];
            q[0] = __floats2half2_rn(acc[i][0], acc[i][1]);
            q[1] = __floats2half2_rn(acc[i][2], acc[i][3]);
            *(float2*)(C + (size_t)gm * N + bn + (tx << 2)) = *(float2*)q;  // 8 B store
        }
    }
}

// ---------------- alpha_s / alpha_d per (node, head), fp16 h ----------------
__global__ __launch_bounds__(256) void alphas_kernel(const __half* __restrict__ hh,
                                                     const float* __restrict__ a_src,
                                                     const float* __restrict__ a_dst,
                                                     float* __restrict__ as_out,
                                                     float* __restrict__ ad_out) {
    int n = blockIdx.x;
    int head = threadIdx.x >> 6;
    int lane = threadIdx.x & 63;
    float2 hv = __half22float2(*(const __half2*)(hh + (size_t)n * F1 + head * 128 + lane * 2));
    float2 sv = *(const float2*)(a_src + head * 128 + lane * 2);
    float2 dv = *(const float2*)(a_dst + head * 128 + lane * 2);
    float s = hv.x * sv.x + hv.y * sv.y;
    float d = hv.x * dv.x + hv.y * dv.y;
    for (int off = 32; off > 0; off >>= 1) {
        s += __shfl_xor(s, off);
        d += __shfl_xor(d, off);
    }
    if (lane == 0) {
        as_out[n * NH + head] = s;
        ad_out[n * NH + head] = d;
    }
}

// ---------------- softmax pass A: writes packed (src, w) per head ----------------
__global__ __launch_bounds__(256) void passA(const int* __restrict__ offsets,
                                             const int* __restrict__ csr,
                                             const float* __restrict__ as,
                                             const float* __restrict__ ad,
                                             float2* __restrict__ epk,
                                             float* __restrict__ invd) {
    int n = blockIdx.x * 4 + (threadIdx.x >> 6);
    int lane = threadIdx.x & 63;
    int start = offsets[n], end = offsets[n + 1];
    float4 adv = *(const float4*)&ad[n * NH];
    float m0 = -1e30f, m1 = -1e30f, m2 = -1e30f, m3 = -1e30f;
    for (int idx = start + lane; idx < end; idx += 64) {
        int src = csr[idx];
        float4 asv = *(const float4*)&as[src * NH];
        m0 = fmaxf(m0, lrelu(asv.x + adv.x));
        m1 = fmaxf(m1, lrelu(asv.y + adv.y));
        m2 = fmaxf(m2, lrelu(asv.z + adv.z));
        m3 = fmaxf(m3, lrelu(asv.w + adv.w));
    }
    for (int off = 32; off > 0; off >>= 1) {
        m0 = fmaxf(m0, __shfl_xor(m0, off));
        m1 = fmaxf(m1, __shfl_xor(m1, off));
        m2 = fmaxf(m2, __shfl_xor(m2, off));
        m3 = fmaxf(m3, __shfl_xor(m3, off));
    }
    float s0 = 0.f, s1 = 0.f, s2 = 0.f, s3 = 0.f;
    for (int idx = start + lane; idx < end; idx += 64) {
        int src = csr[idx];
        float4 asv = *(const float4*)&as[src * NH];
        float e0 = __expf(lrelu(asv.x + adv.x) - m0);
        float e1 = __expf(lrelu(asv.y + adv.y) - m1);
        float e2 = __expf(lrelu(asv.z + adv.z) - m2);
        float e3 = __expf(lrelu(asv.w + adv.w) - m3);
        float fs = __int_as_float(src);
        epk[idx] = make_float2(fs, e0);
        epk[EE + idx] = make_float2(fs, e1);
        epk[2 * EE + idx] = make_float2(fs, e2);
        epk[3 * EE + idx] = make_float2(fs, e3);
        s0 += e0; s1 += e1; s2 += e2; s3 += e3;
    }
    for (int off = 32; off > 0; off >>= 1) {
        s0 += __shfl_xor(s0, off);
        s1 += __shfl_xor(s1, off);
        s2 += __shfl_xor(s2, off);
        s3 += __shfl_xor(s3, off);
    }
    if (lane == 0) {
        *(float4*)&invd[n * NH] = make_float4(1.f / (s0 + 1e-16f), 1.f / (s1 + 1e-16f),
                                              1.f / (s2 + 1e-16f), 1.f / (s3 + 1e-16f));
    }
}

// ---------------- pass B layer 1: XCD-sliced, eighth-wave fp16 gather ----------------
// slice = blockIdx&7 -> XCD; 64 ch/slice fp16 (1.28 MB, L2-resident).
// Wave: eg = lane>>3 covers 8 edges/iter, cg = lane&7 covers 64 ch as 8 halves (16 B).
__global__ __launch_bounds__(256) void passB1h(const int* __restrict__ offsets,
                                               const float2* __restrict__ epk,
                                               const float* __restrict__ invd,
                                               const __half* __restrict__ hh,
                                               const float* __restrict__ b1,
                                               float* __restrict__ agg) {
    int slice = blockIdx.x & 7;
    int n = (blockIdx.x >> 3) * 4 + (threadIdx.x >> 6);
    int lane = threadIdx.x & 63;
    int eg = lane >> 3, cg = lane & 7;
    int head = slice >> 1;
    int c = slice * 64 + (cg << 3);
    int start = offsets[n], end = offsets[n + 1];
    const float2* ep = epk + (size_t)head * EE;
    float acc[8] = {};
    int idx = start + eg;
    float2 p = (idx < end) ? ep[idx] : make_float2(0.f, 0.f);
    while (idx < end) {
        int nidx = idx + 8;
        float2 pn = (nidx < end) ? ep[nidx] : make_float2(0.f, 0.f);
        int s = __float_as_int(p.x);
        float w = p.y;
        float4 raw = *(const float4*)(hh + (size_t)s * F1 + c);
        const __half2* hp = (const __half2*)&raw;
#pragma unroll
        for (int j = 0; j < 4; j++) {
            float2 f = __half22float2(hp[j]);
            acc[2 * j] += f.x * w;
            acc[2 * j + 1] += f.y * w;
        }
        idx = nidx; p = pn;
    }
#pragma unroll
    for (int j = 0; j < 8; j++) {
        acc[j] += __shfl_xor(acc[j], 8);
        acc[j] += __shfl_xor(acc[j], 16);
        acc[j] += __shfl_xor(acc[j], 32);
    }
    if (eg == 0) {
        float inv = invd[n * NH + head];
        float4 b0 = *(const float4*)&b1[c];
        float4 b4 = *(const float4*)&b1[c + 4];
        float4 o0, o1;
        o0.x = fmaxf(acc[0] * inv + b0.x, 0.f);
        o0.y = fmaxf(acc[1] * inv + b0.y, 0.f);
        o0.z = fmaxf(acc[2] * inv + b0.z, 0.f);
        o0.w = fmaxf(acc[3] * inv + b0.w, 0.f);
        o1.x = fmaxf(acc[4] * inv + b4.x, 0.f);
        o1.y = fmaxf(acc[5] * inv + b4.y, 0.f);
        o1.z = fmaxf(acc[6] * inv + b4.z, 0.f);
        o1.w = fmaxf(acc[7] * inv + b4.w, 0.f);
        *(float4*)&agg[(size_t)n * F1 + c] = o0;
        *(float4*)&agg[(size_t)n * F1 + c + 4] = o1;
    }
}

// ---------------- pass B layer 2: eighth-wave fp16 gather -> per-slice tmp ----------------
__global__ __launch_bounds__(256) void passB2h(const int* __restrict__ offsets,
                                               const float2* __restrict__ epk,
                                               const float* __restrict__ invd,
                                               const __half* __restrict__ hh,
                                               float* __restrict__ tmp) {
    int slice = blockIdx.x & 7;
    int n = (blockIdx.x >> 3) * 4 + (threadIdx.x >> 6);
    int lane = threadIdx.x & 63;
    int eg = lane >> 3, cg = lane & 7;
    int head = slice >> 1;
    int c = slice * 64 + (cg << 3);
    int start = offsets[n], end = offsets[n + 1];
    const float2* ep = epk + (size_t)head * EE;
    float acc[8] = {};
    int idx = start + eg;
    float2 p = (idx < end) ? ep[idx] : make_float2(0.f, 0.f);
    while (idx < end) {
        int nidx = idx + 8;
        float2 pn = (nidx < end) ? ep[nidx] : make_float2(0.f, 0.f);
        int s = __float_as_int(p.x);
        float w = p.y;
        float4 raw = *(const float4*)(hh + (size_t)s * F2 + c);
        const __half2* hp = (const __half2*)&raw;
#pragma unroll
        for (int j = 0; j < 4; j++) {
            float2 f = __half22float2(hp[j]);
            acc[2 * j] += f.x * w;
            acc[2 * j + 1] += f.y * w;
        }
        idx = nidx; p = pn;
    }
#pragma unroll
    for (int j = 0; j < 8; j++) {
        acc[j] += __shfl_xor(acc[j], 8);
        acc[j] += __shfl_xor(acc[j], 16);
        acc[j] += __shfl_xor(acc[j], 32);
    }
    if (eg == 0) {
        float q = 0.25f * invd[n * NH + head];
        float4 o0 = make_float4(acc[0] * q, acc[1] * q, acc[2] * q, acc[3] * q);
        float4 o1 = make_float4(acc[4] * q, acc[5] * q, acc[6] * q, acc[7] * q);
        float* tp = tmp + (size_t)slice * Nn * 64 + (size_t)n * 64 + (cg << 3);
        *(float4*)tp = o0;
        *(float4*)(tp + 4) = o1;
    }
}

// ---------------- reduce 4 heads + bias -> d_out ----------------
__global__ void reduce4(const float* __restrict__ tmp, const float* __restrict__ b2,
                        float* __restrict__ out) {
    int i = blockIdx.x * 256 + threadIdx.x;
    if (i >= Nn * OUTC) return;
    int n = i >> 7, oc = i & 127;
    int half = oc >> 6, ch = oc & 63;
    size_t base = (size_t)n * 64 + ch;
    const size_t S = (size_t)Nn * 64;
    float v = tmp[(0 + half) * S + base] + tmp[(2 + half) * S + base] +
              tmp[(4 + half) * S + base] + tmp[(6 + half) * S + base];
    out[i] = v + b2[oc];
}

extern "C" void kernel_launch(void* const* d_in, const int* in_sizes, int n_in,
                              void* d_out, int out_size, void* d_ws, size_t ws_size,
                              hipStream_t stream) {
    const float* x      = (const float*)d_in[0];
    const int*   ei     = (const int*)d_in[1];
    const float* W1     = (const float*)d_in[2];
    const float* a_src1 = (const float*)d_in[3];
    const float* a_dst1 = (const float*)d_in[4];
    const float* b1     = (const float*)d_in[5];
    const float* W2     = (const float*)d_in[6];
    const float* a_src2 = (const float*)d_in[7];
    const float* a_dst2 = (const float*)d_in[8];
    const float* b2     = (const float*)d_in[9];
    float* out = (float*)d_out;

    const size_t NF = (size_t)Nn * F1;
    float* f = (float*)d_ws;
    float* agg1  = f;                    // fp32 GEMM2 input; later aliased as tmp (dead after GEMM2)
    float* tmp   = agg1;
    float* as1   = agg1 + NF;
    float* ad1   = as1 + Nn * NH;
    float* as2   = ad1 + Nn * NH;
    float* ad2   = as2 + Nn * NH;
    float* invd1 = ad2 + Nn * NH;
    float* invd2 = invd1 + Nn * NH;
    float2* epk  = (float2*)(invd2 + Nn * NH);   // NH*EE float2, [head][edge] = (src,w)
    __half* hh   = (__half*)(epk + (size_t)NH * EE);  // NF halves; layer1 h then layer2 h
    int* counts    = (int*)(hh + NF);
    int* offsets   = counts + Nn;
    int* cursor    = offsets + Nn + 1;
    int* csr       = cursor + Nn;
    int* blocksums = csr + EE;

    // CSR build
    init_counts<<<(Nn + 255) / 256, 256, 0, stream>>>(counts);
    count_edges<<<(Ee + 255) / 256, 256, 0, stream>>>(ei, counts);
    reduce_counts<<<NB, 256, 0, stream>>>(counts, blocksums);
    scan_sums<<<1, 64, 0, stream>>>(blocksums);
    scan_final<<<NB, 256, 0, stream>>>(counts, blocksums, offsets, cursor);
    scatter_edges<<<(EE + 255) / 256, 256, 0, stream>>>(ei, cursor, csr);

    // Layer 1
    gemm_f16<<<dim3((Nn + 63) / 64, F1 / 64), 256, 0, stream>>>(x, W1, hh, Nn, F1, INF_);
    alphas_kernel<<<Nn, 256, 0, stream>>>(hh, a_src1, a_dst1, as1, ad1);
    passA<<<Nn / 4, 256, 0, stream>>>(offsets, csr, as1, ad1, epk, invd1);
    passB1h<<<(Nn / 4) * 8, 256, 0, stream>>>(offsets, epk, invd1, hh, b1, agg1);

    // Layer 2
    gemm_f16<<<dim3((Nn + 63) / 64, F2 / 64), 256, 0, stream>>>(agg1, W2, hh, Nn, F2, F1);
    alphas_kernel<<<Nn, 256, 0, stream>>>(hh, a_src2, a_dst2, as2, ad2);
    passA<<<Nn / 4, 256, 0, stream>>>(offsets, csr, as2, ad2, epk, invd2);
    passB2h<<<(Nn / 4) * 8, 256, 0, stream>>>(offsets, epk, invd2, hh, tmp);
    reduce4<<<(Nn * OUTC + 255) / 256, 256, 0, stream>>>(tmp, b2, out);
}

// Round 6
// 284.771 us; speedup vs baseline: 1.7527x; 1.2307x over previous
//
#include <hip/hip_runtime.h>
#include <hip/hip_fp16.h>
#include <math.h>

#define Nn 10000
#define Ee 320000
#define EE 330000      // E + N self loops
#define INF_ 256
#define HID 128
#define OUTC 128
#define NH 4
#define F1 512         // NH*HID
#define F2 512         // NH*OUTC
#define SLOPE 0.2f
#define NB 40          // ceil(Nn/256)

static __device__ __forceinline__ float lrelu(float x) { return fmaxf(x, SLOPE * x); }

using frag_ab = __attribute__((ext_vector_type(8))) _Float16;  // 4 VGPRs
using frag_c  = __attribute__((ext_vector_type(4))) float;     // 4 VGPRs

// ---------------- CSR build ----------------
__global__ void init_counts(int* counts) {
    int i = blockIdx.x * 256 + threadIdx.x;
    if (i < Nn) counts[i] = 1;  // self loop
}

__global__ void count_edges(const int* __restrict__ ei, int* counts) {
    int e = blockIdx.x * 256 + threadIdx.x;
    if (e < Ee) atomicAdd(&counts[ei[Ee + e]], 1);
}

__global__ __launch_bounds__(256) void reduce_counts(const int* __restrict__ counts,
                                                     int* __restrict__ blocksums) {
    __shared__ int sd[256];
    int t = threadIdx.x, i = blockIdx.x * 256 + t;
    sd[t] = (i < Nn) ? counts[i] : 0;
    __syncthreads();
    for (int off = 128; off > 0; off >>= 1) {
        if (t < off) sd[t] += sd[t + off];
        __syncthreads();
    }
    if (t == 0) blocksums[blockIdx.x] = sd[0];
}

__global__ __launch_bounds__(64) void scan_sums(int* blocksums) {
    int t = threadIdx.x;
    int orig = (t < NB) ? blocksums[t] : 0;
    int v = orig;
    for (int off = 1; off < 64; off <<= 1) {
        int u = __shfl_up(v, off);
        if (t >= off) v += u;
    }
    if (t < NB) blocksums[t] = v - orig;  // exclusive
}

__global__ __launch_bounds__(256) void scan_final(const int* __restrict__ counts,
                                                  const int* __restrict__ blocksums,
                                                  int* __restrict__ offsets,
                                                  int* __restrict__ cursor) {
    __shared__ int sd[256];
    int t = threadIdx.x, i = blockIdx.x * 256 + t;
    int v = (i < Nn) ? counts[i] : 0;
    sd[t] = v;
    __syncthreads();
    int x = v;
    for (int off = 1; off < 256; off <<= 1) {
        int u = (t >= off) ? sd[t - off] : 0;
        __syncthreads();
        x += u;
        sd[t] = x;
        __syncthreads();
    }
    int base = blocksums[blockIdx.x];
    int e = base + x - v;  // exclusive
    if (i < Nn) {
        offsets[i] = e;
        cursor[i] = e;
        if (i == Nn - 1) offsets[Nn] = e + v;
    }
}

__global__ void scatter_edges(const int* __restrict__ ei, int* cursor, int* __restrict__ csr) {
    int t = blockIdx.x * 256 + threadIdx.x;
    if (t >= EE) return;
    int src, dst;
    if (t < Ee) { src = ei[t]; dst = ei[Ee + t]; }
    else        { src = t - Ee; dst = t - Ee; }
    int pos = atomicAdd(&cursor[dst], 1);
    csr[pos] = src;
}

// ---------------- fp32 -> fp16 conversions ----------------
__global__ void conv_f16(const float* __restrict__ in, _Float16* __restrict__ out, int n) {
    int i = blockIdx.x * 256 + threadIdx.x;
    if (i < n) out[i] = (_Float16)in[i];
}

// W [K x N] fp32 -> WT [N x K] fp16
__global__ void transpose_f16(const float* __restrict__ W, _Float16* __restrict__ WT,
                              int K, int N) {
    int n = blockIdx.x * 64 + (threadIdx.x & 63);
    int k = blockIdx.y * 4 + (threadIdx.x >> 6);
    if (n < N && k < K) WT[(size_t)n * K + k] = (_Float16)W[(size_t)k * N + n];
}

// ---------------- MFMA fp16 GEMM: C[M,N] = A[M,K] * BT[N,K]^T ----------------
// 64x128 tile, 256 thr = 4 waves; wave w owns rows w*16..+15, 8 col-frags of 16.
// LDS stride 40 halves (80 B: 16B-aligned, bank-rotating).
#define LDK 40
__global__ __launch_bounds__(256) void mfma_gemm(const _Float16* __restrict__ A,
                                                 const _Float16* __restrict__ BT,
                                                 _Float16* __restrict__ C,
                                                 int M, int N, int K) {
    __shared__ _Float16 As[64 * LDK];
    __shared__ _Float16 Bs[128 * LDK];
    const int tid = threadIdx.x;
    const int wave = tid >> 6, lane = tid & 63;
    const int q = lane >> 4, ml = lane & 15;
    const int bm = blockIdx.x * 64, bn = blockIdx.y * 128;
    const int srow = tid >> 2, scol = (tid & 3) * 8;  // staging: row, k-offset

    frag_c acc[8];
#pragma unroll
    for (int f = 0; f < 8; f++)
#pragma unroll
        for (int r = 0; r < 4; r++) acc[f][r] = 0.f;

    for (int k0 = 0; k0 < K; k0 += 32) {
        int gm = bm + srow;
        frag_ab av;
        if (gm < M) av = *(const frag_ab*)(A + (size_t)gm * K + k0 + scol);
        else {
#pragma unroll
            for (int j = 0; j < 8; j++) av[j] = (_Float16)0.f;
        }
        *(frag_ab*)&As[srow * LDK + scol] = av;
        *(frag_ab*)&Bs[srow * LDK + scol] =
            *(const frag_ab*)(BT + (size_t)(bn + srow) * K + k0 + scol);
        *(frag_ab*)&Bs[(64 + srow) * LDK + scol] =
            *(const frag_ab*)(BT + (size_t)(bn + 64 + srow) * K + k0 + scol);
        __syncthreads();
        frag_ab a = *(frag_ab*)&As[(wave * 16 + ml) * LDK + q * 8];
#pragma unroll
        for (int f = 0; f < 8; f++) {
            frag_ab b = *(frag_ab*)&Bs[(f * 16 + ml) * LDK + q * 8];
            acc[f] = __builtin_amdgcn_mfma_f32_16x16x32_f16(a, b, acc[f], 0, 0, 0);
        }
        __syncthreads();
    }
    // C/D layout: row = q*4 + r (within wave strip), col = ml
#pragma unroll
    for (int f = 0; f < 8; f++) {
        int col = bn + f * 16 + ml;
#pragma unroll
        for (int r = 0; r < 4; r++) {
            int row = bm + wave * 16 + q * 4 + r;
            if (row < M) C[(size_t)row * N + col] = (_Float16)acc[f][r];
        }
    }
}

// ---------------- alpha_s / alpha_d per (node, head), fp16 h ----------------
__global__ __launch_bounds__(256) void alphas_kernel(const __half* __restrict__ hh,
                                                     const float* __restrict__ a_src,
                                                     const float* __restrict__ a_dst,
                                                     float* __restrict__ as_out,
                                                     float* __restrict__ ad_out) {
    int n = blockIdx.x;
    int head = threadIdx.x >> 6;
    int lane = threadIdx.x & 63;
    float2 hv = __half22float2(*(const __half2*)(hh + (size_t)n * F1 + head * 128 + lane * 2));
    float2 sv = *(const float2*)(a_src + head * 128 + lane * 2);
    float2 dv = *(const float2*)(a_dst + head * 128 + lane * 2);
    float s = hv.x * sv.x + hv.y * sv.y;
    float d = hv.x * dv.x + hv.y * dv.y;
    for (int off = 32; off > 0; off >>= 1) {
        s += __shfl_xor(s, off);
        d += __shfl_xor(d, off);
    }
    if (lane == 0) {
        as_out[n * NH + head] = s;
        ad_out[n * NH + head] = d;
    }
}

// ---------------- softmax pass A: writes packed (src, w) per head ----------------
__global__ __launch_bounds__(256) void passA(const int* __restrict__ offsets,
                                             const int* __restrict__ csr,
                                             const float* __restrict__ as,
                                             const float* __restrict__ ad,
                                             float2* __restrict__ epk,
                                             float* __restrict__ invd) {
    int n = blockIdx.x * 4 + (threadIdx.x >> 6);
    int lane = threadIdx.x & 63;
    int start = offsets[n], end = offsets[n + 1];
    float4 adv = *(const float4*)&ad[n * NH];
    float m0 = -1e30f, m1 = -1e30f, m2 = -1e30f, m3 = -1e30f;
    for (int idx = start + lane; idx < end; idx += 64) {
        int src = csr[idx];
        float4 asv = *(const float4*)&as[src * NH];
        m0 = fmaxf(m0, lrelu(asv.x + adv.x));
        m1 = fmaxf(m1, lrelu(asv.y + adv.y));
        m2 = fmaxf(m2, lrelu(asv.z + adv.z));
        m3 = fmaxf(m3, lrelu(asv.w + adv.w));
    }
    for (int off = 32; off > 0; off >>= 1) {
        m0 = fmaxf(m0, __shfl_xor(m0, off));
        m1 = fmaxf(m1, __shfl_xor(m1, off));
        m2 = fmaxf(m2, __shfl_xor(m2, off));
        m3 = fmaxf(m3, __shfl_xor(m3, off));
    }
    float s0 = 0.f, s1 = 0.f, s2 = 0.f, s3 = 0.f;
    for (int idx = start + lane; idx < end; idx += 64) {
        int src = csr[idx];
        float4 asv = *(const float4*)&as[src * NH];
        float e0 = __expf(lrelu(asv.x + adv.x) - m0);
        float e1 = __expf(lrelu(asv.y + adv.y) - m1);
        float e2 = __expf(lrelu(asv.z + adv.z) - m2);
        float e3 = __expf(lrelu(asv.w + adv.w) - m3);
        float fs = __int_as_float(src);
        epk[idx] = make_float2(fs, e0);
        epk[EE + idx] = make_float2(fs, e1);
        epk[2 * EE + idx] = make_float2(fs, e2);
        epk[3 * EE + idx] = make_float2(fs, e3);
        s0 += e0; s1 += e1; s2 += e2; s3 += e3;
    }
    for (int off = 32; off > 0; off >>= 1) {
        s0 += __shfl_xor(s0, off);
        s1 += __shfl_xor(s1, off);
        s2 += __shfl_xor(s2, off);
        s3 += __shfl_xor(s3, off);
    }
    if (lane == 0) {
        *(float4*)&invd[n * NH] = make_float4(1.f / (s0 + 1e-16f), 1.f / (s1 + 1e-16f),
                                              1.f / (s2 + 1e-16f), 1.f / (s3 + 1e-16f));
    }
}

// ---------------- pass B layer 1: XCD-sliced eighth-wave fp16 gather -> fp16 agg ----------------
__global__ __launch_bounds__(256) void passB1h(const int* __restrict__ offsets,
                                               const float2* __restrict__ epk,
                                               const float* __restrict__ invd,
                                               const __half* __restrict__ hh,
                                               const float* __restrict__ b1,
                                               _Float16* __restrict__ agg) {
    int slice = blockIdx.x & 7;
    int n = (blockIdx.x >> 3) * 4 + (threadIdx.x >> 6);
    int lane = threadIdx.x & 63;
    int eg = lane >> 3, cg = lane & 7;
    int head = slice >> 1;
    int c = slice * 64 + (cg << 3);
    int start = offsets[n], end = offsets[n + 1];
    const float2* ep = epk + (size_t)head * EE;
    float acc[8] = {};
    int idx = start + eg;
    float2 p = (idx < end) ? ep[idx] : make_float2(0.f, 0.f);
    while (idx < end) {
        int nidx = idx + 8;
        float2 pn = (nidx < end) ? ep[nidx] : make_float2(0.f, 0.f);
        int s = __float_as_int(p.x);
        float w = p.y;
        float4 raw = *(const float4*)(hh + (size_t)s * F1 + c);
        const __half2* hp = (const __half2*)&raw;
#pragma unroll
        for (int j = 0; j < 4; j++) {
            float2 f = __half22float2(hp[j]);
            acc[2 * j] += f.x * w;
            acc[2 * j + 1] += f.y * w;
        }
        idx = nidx; p = pn;
    }
#pragma unroll
    for (int j = 0; j < 8; j++) {
        acc[j] += __shfl_xor(acc[j], 8);
        acc[j] += __shfl_xor(acc[j], 16);
        acc[j] += __shfl_xor(acc[j], 32);
    }
    if (eg == 0) {
        float inv = invd[n * NH + head];
        _Float16 oh[8];
#pragma unroll
        for (int j = 0; j < 8; j++)
            oh[j] = (_Float16)fmaxf(acc[j] * inv + b1[c + j], 0.f);
        *(float4*)&agg[(size_t)n * F1 + c] = *(float4*)oh;  // 16 B
    }
}

// ---------------- pass B layer 2: eighth-wave fp16 gather -> per-slice tmp ----------------
__global__ __launch_bounds__(256) void passB2h(const int* __restrict__ offsets,
                                               const float2* __restrict__ epk,
                                               const float* __restrict__ invd,
                                               const __half* __restrict__ hh,
                                               float* __restrict__ tmp) {
    int slice = blockIdx.x & 7;
    int n = (blockIdx.x >> 3) * 4 + (threadIdx.x >> 6);
    int lane = threadIdx.x & 63;
    int eg = lane >> 3, cg = lane & 7;
    int head = slice >> 1;
    int c = slice * 64 + (cg << 3);
    int start = offsets[n], end = offsets[n + 1];
    const float2* ep = epk + (size_t)head * EE;
    float acc[8] = {};
    int idx = start + eg;
    float2 p = (idx < end) ? ep[idx] : make_float2(0.f, 0.f);
    while (idx < end) {
        int nidx = idx + 8;
        float2 pn = (nidx < end) ? ep[nidx] : make_float2(0.f, 0.f);
        int s = __float_as_int(p.x);
        float w = p.y;
        float4 raw = *(const float4*)(hh + (size_t)s * F2 + c);
        const __half2* hp = (const __half2*)&raw;
#pragma unroll
        for (int j = 0; j < 4; j++) {
            float2 f = __half22float2(hp[j]);
            acc[2 * j] += f.x * w;
            acc[2 * j + 1] += f.y * w;
        }
        idx = nidx; p = pn;
    }
#pragma unroll
    for (int j = 0; j < 8; j++) {
        acc[j] += __shfl_xor(acc[j], 8);
        acc[j] += __shfl_xor(acc[j], 16);
        acc[j] += __shfl_xor(acc[j], 32);
    }
    if (eg == 0) {
        float q = 0.25f * invd[n * NH + head];
        float4 o0 = make_float4(acc[0] * q, acc[1] * q, acc[2] * q, acc[3] * q);
        float4 o1 = make_float4(acc[4] * q, acc[5] * q, acc[6] * q, acc[7] * q);
        float* tp = tmp + (size_t)slice * Nn * 64 + (size_t)n * 64 + (cg << 3);
        *(float4*)tp = o0;
        *(float4*)(tp + 4) = o1;
    }
}

// ---------------- reduce 4 heads + bias -> d_out ----------------
__global__ void reduce4(const float* __restrict__ tmp, const float* __restrict__ b2,
                        float* __restrict__ out) {
    int i = blockIdx.x * 256 + threadIdx.x;
    if (i >= Nn * OUTC) return;
    int n = i >> 7, oc = i & 127;
    int half_ = oc >> 6, ch = oc & 63;
    size_t base = (size_t)n * 64 + ch;
    const size_t S = (size_t)Nn * 64;
    float v = tmp[(0 + half_) * S + base] + tmp[(2 + half_) * S + base] +
              tmp[(4 + half_) * S + base] + tmp[(6 + half_) * S + base];
    out[i] = v + b2[oc];
}

extern "C" void kernel_launch(void* const* d_in, const int* in_sizes, int n_in,
                              void* d_out, int out_size, void* d_ws, size_t ws_size,
                              hipStream_t stream) {
    const float* x      = (const float*)d_in[0];
    const int*   ei     = (const int*)d_in[1];
    const float* W1     = (const float*)d_in[2];
    const float* a_src1 = (const float*)d_in[3];
    const float* a_dst1 = (const float*)d_in[4];
    const float* b1     = (const float*)d_in[5];
    const float* W2     = (const float*)d_in[6];
    const float* a_src2 = (const float*)d_in[7];
    const float* a_dst2 = (const float*)d_in[8];
    const float* b2     = (const float*)d_in[9];
    float* out = (float*)d_out;

    const size_t NF = (size_t)Nn * F1;   // 5,120,000
    float* f = (float*)d_ws;
    float* tmp   = f;                    // NF floats (head partials, layer 2)
    float* as1   = tmp + NF;
    float* ad1   = as1 + Nn * NH;
    float* as2   = ad1 + Nn * NH;
    float* ad2   = as2 + Nn * NH;
    float* invd1 = ad2 + Nn * NH;
    float* invd2 = invd1 + Nn * NH;
    float2* epk  = (float2*)(invd2 + Nn * NH);       // NH*EE float2
    _Float16* hh   = (_Float16*)(epk + (size_t)NH * EE);  // NF halves
    _Float16* aggh = hh + NF;                             // NF halves
    _Float16* xh   = aggh + NF;                           // Nn*INF_ halves
    _Float16* w1t  = xh + (size_t)Nn * INF_;              // F1*INF_ halves
    _Float16* w2t  = w1t + (size_t)F1 * INF_;             // F2*F1 halves
    int* counts    = (int*)(w2t + (size_t)F2 * F1);
    int* offsets   = counts + Nn;
    int* cursor    = offsets + Nn + 1;
    int* csr       = cursor + Nn;
    int* blocksums = csr + EE;

    // CSR build
    init_counts<<<(Nn + 255) / 256, 256, 0, stream>>>(counts);
    count_edges<<<(Ee + 255) / 256, 256, 0, stream>>>(ei, counts);
    reduce_counts<<<NB, 256, 0, stream>>>(counts, blocksums);
    scan_sums<<<1, 64, 0, stream>>>(blocksums);
    scan_final<<<NB, 256, 0, stream>>>(counts, blocksums, offsets, cursor);
    scatter_edges<<<(EE + 255) / 256, 256, 0, stream>>>(ei, cursor, csr);

    // fp16 conversions
    conv_f16<<<(Nn * INF_ + 255) / 256, 256, 0, stream>>>(x, xh, Nn * INF_);
    transpose_f16<<<dim3(F1 / 64, INF_ / 4), 256, 0, stream>>>(W1, w1t, INF_, F1);
    transpose_f16<<<dim3(F2 / 64, F1 / 4), 256, 0, stream>>>(W2, w2t, F1, F2);

    // Layer 1: h = x @ W1  (MFMA fp16)
    mfma_gemm<<<dim3((Nn + 63) / 64, F1 / 128), 256, 0, stream>>>(xh, w1t, hh, Nn, F1, INF_);
    alphas_kernel<<<Nn, 256, 0, stream>>>((const __half*)hh, a_src1, a_dst1, as1, ad1);
    passA<<<Nn / 4, 256, 0, stream>>>(offsets, csr, as1, ad1, epk, invd1);
    passB1h<<<(Nn / 4) * 8, 256, 0, stream>>>(offsets, epk, invd1, (const __half*)hh, b1, aggh);

    // Layer 2: h2 = agg @ W2  (MFMA fp16)
    mfma_gemm<<<dim3((Nn + 63) / 64, F2 / 128), 256, 0, stream>>>(aggh, w2t, hh, Nn, F2, F1);
    alphas_kernel<<<Nn, 256, 0, stream>>>((const __half*)hh, a_src2, a_dst2, as2, ad2);
    passA<<<Nn / 4, 256, 0, stream>>>(offsets, csr, as2, ad2, epk, invd2);
    passB2h<<<(Nn / 4) * 8, 256, 0, stream>>>(offsets, epk, invd2, (const __half*)hh, tmp);
    reduce4<<<(Nn * OUTC + 255) / 256, 256, 0, stream>>>(tmp, b2, out);
}

// Round 7
// 267.680 us; speedup vs baseline: 1.8646x; 1.0638x over previous
//
#include <hip/hip_runtime.h>
#include <hip/hip_fp16.h>
#include <math.h>

#define Nn 10000
#define Ee 320000
#define EE 330000      // E + N self loops
#define INF_ 256
#define HID 128
#define OUTC 128
#define NH 4
#define F1 512         // NH*HID
#define F2 512         // NH*OUTC
#define SLOPE 0.2f
#define NB 40          // ceil(Nn/256)

static __device__ __forceinline__ float lrelu(float x) { return fmaxf(x, SLOPE * x); }

using frag_ab = __attribute__((ext_vector_type(8))) _Float16;  // 4 VGPRs
using frag_c  = __attribute__((ext_vector_type(4))) float;     // 4 VGPRs

// ---------------- CSR build ----------------
__global__ void init_counts(int* counts) {
    int i = blockIdx.x * 256 + threadIdx.x;
    if (i < Nn) counts[i] = 1;  // self loop
}

__global__ void count_edges(const int* __restrict__ ei, int* counts) {
    int e = blockIdx.x * 256 + threadIdx.x;
    if (e < Ee) atomicAdd(&counts[ei[Ee + e]], 1);
}

__global__ __launch_bounds__(256) void reduce_counts(const int* __restrict__ counts,
                                                     int* __restrict__ blocksums) {
    __shared__ int sd[256];
    int t = threadIdx.x, i = blockIdx.x * 256 + t;
    sd[t] = (i < Nn) ? counts[i] : 0;
    __syncthreads();
    for (int off = 128; off > 0; off >>= 1) {
        if (t < off) sd[t] += sd[t + off];
        __syncthreads();
    }
    if (t == 0) blocksums[blockIdx.x] = sd[0];
}

__global__ __launch_bounds__(64) void scan_sums(int* blocksums) {
    int t = threadIdx.x;
    int orig = (t < NB) ? blocksums[t] : 0;
    int v = orig;
    for (int off = 1; off < 64; off <<= 1) {
        int u = __shfl_up(v, off);
        if (t >= off) v += u;
    }
    if (t < NB) blocksums[t] = v - orig;  // exclusive
}

__global__ __launch_bounds__(256) void scan_final(const int* __restrict__ counts,
                                                  const int* __restrict__ blocksums,
                                                  int* __restrict__ offsets,
                                                  int* __restrict__ cursor) {
    __shared__ int sd[256];
    int t = threadIdx.x, i = blockIdx.x * 256 + t;
    int v = (i < Nn) ? counts[i] : 0;
    sd[t] = v;
    __syncthreads();
    int x = v;
    for (int off = 1; off < 256; off <<= 1) {
        int u = (t >= off) ? sd[t - off] : 0;
        __syncthreads();
        x += u;
        sd[t] = x;
        __syncthreads();
    }
    int base = blocksums[blockIdx.x];
    int e = base + x - v;  // exclusive
    if (i < Nn) {
        offsets[i] = e;
        cursor[i] = e;
        if (i == Nn - 1) offsets[Nn] = e + v;
    }
}

__global__ void scatter_edges(const int* __restrict__ ei, int* cursor, int* __restrict__ csr) {
    int t = blockIdx.x * 256 + threadIdx.x;
    if (t >= EE) return;
    int src, dst;
    if (t < Ee) { src = ei[t]; dst = ei[Ee + t]; }
    else        { src = t - Ee; dst = t - Ee; }
    int pos = atomicAdd(&cursor[dst], 1);
    csr[pos] = src;
}

// ---------------- fp32 -> fp16 conversions ----------------
__global__ void conv_f16(const float* __restrict__ in, _Float16* __restrict__ out, int n) {
    int i = blockIdx.x * 256 + threadIdx.x;
    if (i < n) out[i] = (_Float16)in[i];
}

// W [K x N] fp32 -> WT [N x K] fp16
__global__ void transpose_f16(const float* __restrict__ W, _Float16* __restrict__ WT,
                              int K, int N) {
    int n = blockIdx.x * 64 + (threadIdx.x & 63);
    int k = blockIdx.y * 4 + (threadIdx.x >> 6);
    if (n < N && k < K) WT[(size_t)n * K + k] = (_Float16)W[(size_t)k * N + n];
}

// ---------------- MFMA fp16 GEMM + fused alpha dots ----------------
// C[M,N] = A[M,K] * BT[N,K]^T ; 64x128 tile, 4 waves, 8 col-frags/wave.
// blockIdx.y covers 128 cols == one head; epilogue computes
// as[row,head] = sum_c accrow[c]*a_src[head][c] (and ad) via 16-lane reduce.
#define LDK 40
__global__ __launch_bounds__(256) void mfma_gemm(const _Float16* __restrict__ A,
                                                 const _Float16* __restrict__ BT,
                                                 _Float16* __restrict__ C,
                                                 const float* __restrict__ a_src,
                                                 const float* __restrict__ a_dst,
                                                 float* __restrict__ as_out,
                                                 float* __restrict__ ad_out,
                                                 int M, int K) {
    __shared__ _Float16 As[64 * LDK];
    __shared__ _Float16 Bs[128 * LDK];
    const int tid = threadIdx.x;
    const int wave = tid >> 6, lane = tid & 63;
    const int q = lane >> 4, ml = lane & 15;
    const int bm = blockIdx.x * 64, bn = blockIdx.y * 128;
    const int head = blockIdx.y;
    const int srow = tid >> 2, scol = (tid & 3) * 8;

    frag_c acc[8];
#pragma unroll
    for (int f = 0; f < 8; f++)
#pragma unroll
        for (int r = 0; r < 4; r++) acc[f][r] = 0.f;

    for (int k0 = 0; k0 < K; k0 += 32) {
        int gm = bm + srow;
        frag_ab av;
        if (gm < M) av = *(const frag_ab*)(A + (size_t)gm * K + k0 + scol);
        else {
#pragma unroll
            for (int j = 0; j < 8; j++) av[j] = (_Float16)0.f;
        }
        *(frag_ab*)&As[srow * LDK + scol] = av;
        *(frag_ab*)&Bs[srow * LDK + scol] =
            *(const frag_ab*)(BT + (size_t)(bn + srow) * K + k0 + scol);
        *(frag_ab*)&Bs[(64 + srow) * LDK + scol] =
            *(const frag_ab*)(BT + (size_t)(bn + 64 + srow) * K + k0 + scol);
        __syncthreads();
        frag_ab a = *(frag_ab*)&As[(wave * 16 + ml) * LDK + q * 8];
#pragma unroll
        for (int f = 0; f < 8; f++) {
            frag_ab b = *(frag_ab*)&Bs[(f * 16 + ml) * LDK + q * 8];
            acc[f] = __builtin_amdgcn_mfma_f32_16x16x32_f16(a, b, acc[f], 0, 0, 0);
        }
        __syncthreads();
    }
    // C store + alpha partials. C/D: row = wave*16 + q*4 + r, col = f*16 + ml.
    float asum[4] = {}, dsum[4] = {};
#pragma unroll
    for (int f = 0; f < 8; f++) {
        int cl = f * 16 + ml;                  // 0..127 within head
        int col = bn + cl;
        float sa = a_src[head * 128 + cl];
        float da = a_dst[head * 128 + cl];
#pragma unroll
        for (int r = 0; r < 4; r++) {
            int row = bm + wave * 16 + q * 4 + r;
            if (row < M) C[(size_t)row * (NH * 128) + col] = (_Float16)acc[f][r];
            asum[r] += acc[f][r] * sa;
            dsum[r] += acc[f][r] * da;
        }
    }
#pragma unroll
    for (int r = 0; r < 4; r++) {
#pragma unroll
        for (int off = 1; off < 16; off <<= 1) {
            asum[r] += __shfl_xor(asum[r], off);
            dsum[r] += __shfl_xor(dsum[r], off);
        }
    }
    if (ml == 0) {
#pragma unroll
        for (int r = 0; r < 4; r++) {
            int row = bm + wave * 16 + q * 4 + r;
            if (row < M) {
                as_out[row * NH + head] = asum[r];
                ad_out[row * NH + head] = dsum[r];
            }
        }
    }
}

// ---------------- softmax pass A: quarter-wave (16 lanes) per node ----------------
__global__ __launch_bounds__(256) void passA(const int* __restrict__ offsets,
                                             const int* __restrict__ csr,
                                             const float* __restrict__ as,
                                             const float* __restrict__ ad,
                                             float2* __restrict__ epk,
                                             float* __restrict__ invd) {
    int n = blockIdx.x * 16 + (threadIdx.x >> 4);
    int l = threadIdx.x & 15;
    int start = offsets[n], end = offsets[n + 1];
    float4 adv = *(const float4*)&ad[n * NH];
    float m0 = -1e30f, m1 = -1e30f, m2 = -1e30f, m3 = -1e30f;
    for (int idx = start + l; idx < end; idx += 16) {
        int src = csr[idx];
        float4 asv = *(const float4*)&as[src * NH];
        m0 = fmaxf(m0, lrelu(asv.x + adv.x));
        m1 = fmaxf(m1, lrelu(asv.y + adv.y));
        m2 = fmaxf(m2, lrelu(asv.z + adv.z));
        m3 = fmaxf(m3, lrelu(asv.w + adv.w));
    }
#pragma unroll
    for (int off = 8; off > 0; off >>= 1) {
        m0 = fmaxf(m0, __shfl_xor(m0, off));
        m1 = fmaxf(m1, __shfl_xor(m1, off));
        m2 = fmaxf(m2, __shfl_xor(m2, off));
        m3 = fmaxf(m3, __shfl_xor(m3, off));
    }
    float s0 = 0.f, s1 = 0.f, s2 = 0.f, s3 = 0.f;
    for (int idx = start + l; idx < end; idx += 16) {
        int src = csr[idx];
        float4 asv = *(const float4*)&as[src * NH];
        float e0 = __expf(lrelu(asv.x + adv.x) - m0);
        float e1 = __expf(lrelu(asv.y + adv.y) - m1);
        float e2 = __expf(lrelu(asv.z + adv.z) - m2);
        float e3 = __expf(lrelu(asv.w + adv.w) - m3);
        float fs = __int_as_float(src);
        epk[idx] = make_float2(fs, e0);
        epk[EE + idx] = make_float2(fs, e1);
        epk[2 * EE + idx] = make_float2(fs, e2);
        epk[3 * EE + idx] = make_float2(fs, e3);
        s0 += e0; s1 += e1; s2 += e2; s3 += e3;
    }
#pragma unroll
    for (int off = 8; off > 0; off >>= 1) {
        s0 += __shfl_xor(s0, off);
        s1 += __shfl_xor(s1, off);
        s2 += __shfl_xor(s2, off);
        s3 += __shfl_xor(s3, off);
    }
    if (l == 0) {
        *(float4*)&invd[n * NH] = make_float4(1.f / (s0 + 1e-16f), 1.f / (s1 + 1e-16f),
                                              1.f / (s2 + 1e-16f), 1.f / (s3 + 1e-16f));
    }
}

// ---------------- pass B layer 1: XCD-sliced, eighth-wave, 2 edges/lane ----------------
__global__ __launch_bounds__(256) void passB1h(const int* __restrict__ offsets,
                                               const float2* __restrict__ epk,
                                               const float* __restrict__ invd,
                                               const __half* __restrict__ hh,
                                               const float* __restrict__ b1,
                                               _Float16* __restrict__ agg) {
    int slice = blockIdx.x & 7;
    int n = (blockIdx.x >> 3) * 4 + (threadIdx.x >> 6);
    int lane = threadIdx.x & 63;
    int eg = lane >> 3, cg = lane & 7;
    int head = slice >> 1;
    int c = slice * 64 + (cg << 3);
    int start = offsets[n], end = offsets[n + 1];
    const float2* ep = epk + (size_t)head * EE;
    float acc[8] = {};
    int idx = start + eg;
    float2 p0 = (idx < end) ? ep[idx] : make_float2(0.f, 0.f);
    float2 p1 = (idx + 8 < end) ? ep[idx + 8] : make_float2(0.f, 0.f);
    while (idx < end) {
        int nidx = idx + 16;
        float2 q0 = (nidx < end) ? ep[nidx] : make_float2(0.f, 0.f);
        float2 q1 = (nidx + 8 < end) ? ep[nidx + 8] : make_float2(0.f, 0.f);
        int s0 = __float_as_int(p0.x);
        int s1 = __float_as_int(p1.x);
        float w0 = p0.y, w1 = p1.y;
        float4 raw0 = *(const float4*)(hh + (size_t)s0 * F1 + c);
        float4 raw1 = *(const float4*)(hh + (size_t)s1 * F1 + c);
        const __half2* h0 = (const __half2*)&raw0;
        const __half2* h1 = (const __half2*)&raw1;
#pragma unroll
        for (int j = 0; j < 4; j++) {
            float2 f0 = __half22float2(h0[j]);
            float2 f1 = __half22float2(h1[j]);
            acc[2 * j] += f0.x * w0 + f1.x * w1;
            acc[2 * j + 1] += f0.y * w0 + f1.y * w1;
        }
        idx = nidx; p0 = q0; p1 = q1;
    }
#pragma unroll
    for (int j = 0; j < 8; j++) {
        acc[j] += __shfl_xor(acc[j], 8);
        acc[j] += __shfl_xor(acc[j], 16);
        acc[j] += __shfl_xor(acc[j], 32);
    }
    if (eg == 0) {
        float inv = invd[n * NH + head];
        _Float16 oh[8];
#pragma unroll
        for (int j = 0; j < 8; j++)
            oh[j] = (_Float16)fmaxf(acc[j] * inv + b1[c + j], 0.f);
        *(float4*)&agg[(size_t)n * F1 + c] = *(float4*)oh;  // 16 B
    }
}

// ---------------- pass B layer 2: eighth-wave, 2 edges/lane -> per-slice tmp ----------------
__global__ __launch_bounds__(256) void passB2h(const int* __restrict__ offsets,
                                               const float2* __restrict__ epk,
                                               const float* __restrict__ invd,
                                               const __half* __restrict__ hh,
                                               float* __restrict__ tmp) {
    int slice = blockIdx.x & 7;
    int n = (blockIdx.x >> 3) * 4 + (threadIdx.x >> 6);
    int lane = threadIdx.x & 63;
    int eg = lane >> 3, cg = lane & 7;
    int head = slice >> 1;
    int c = slice * 64 + (cg << 3);
    int start = offsets[n], end = offsets[n + 1];
    const float2* ep = epk + (size_t)head * EE;
    float acc[8] = {};
    int idx = start + eg;
    float2 p0 = (idx < end) ? ep[idx] : make_float2(0.f, 0.f);
    float2 p1 = (idx + 8 < end) ? ep[idx + 8] : make_float2(0.f, 0.f);
    while (idx < end) {
        int nidx = idx + 16;
        float2 q0 = (nidx < end) ? ep[nidx] : make_float2(0.f, 0.f);
        float2 q1 = (nidx + 8 < end) ? ep[nidx + 8] : make_float2(0.f, 0.f);
        int s0 = __float_as_int(p0.x);
        int s1 = __float_as_int(p1.x);
        float w0 = p0.y, w1 = p1.y;
        float4 raw0 = *(const float4*)(hh + (size_t)s0 * F2 + c);
        float4 raw1 = *(const float4*)(hh + (size_t)s1 * F2 + c);
        const __half2* h0 = (const __half2*)&raw0;
        const __half2* h1 = (const __half2*)&raw1;
#pragma unroll
        for (int j = 0; j < 4; j++) {
            float2 f0 = __half22float2(h0[j]);
            float2 f1 = __half22float2(h1[j]);
            acc[2 * j] += f0.x * w0 + f1.x * w1;
            acc[2 * j + 1] += f0.y * w0 + f1.y * w1;
        }
        idx = nidx; p0 = q0; p1 = q1;
    }
#pragma unroll
    for (int j = 0; j < 8; j++) {
        acc[j] += __shfl_xor(acc[j], 8);
        acc[j] += __shfl_xor(acc[j], 16);
        acc[j] += __shfl_xor(acc[j], 32);
    }
    if (eg == 0) {
        float q = 0.25f * invd[n * NH + head];
        float4 o0 = make_float4(acc[0] * q, acc[1] * q, acc[2] * q, acc[3] * q);
        float4 o1 = make_float4(acc[4] * q, acc[5] * q, acc[6] * q, acc[7] * q);
        float* tp = tmp + (size_t)slice * Nn * 64 + (size_t)n * 64 + (cg << 3);
        *(float4*)tp = o0;
        *(float4*)(tp + 4) = o1;
    }
}

// ---------------- reduce 4 heads + bias -> d_out ----------------
__global__ void reduce4(const float* __restrict__ tmp, const float* __restrict__ b2,
                        float* __restrict__ out) {
    int i = blockIdx.x * 256 + threadIdx.x;
    if (i >= Nn * OUTC) return;
    int n = i >> 7, oc = i & 127;
    int half_ = oc >> 6, ch = oc & 63;
    size_t base = (size_t)n * 64 + ch;
    const size_t S = (size_t)Nn * 64;
    float v = tmp[(0 + half_) * S + base] + tmp[(2 + half_) * S + base] +
              tmp[(4 + half_) * S + base] + tmp[(6 + half_) * S + base];
    out[i] = v + b2[oc];
}

extern "C" void kernel_launch(void* const* d_in, const int* in_sizes, int n_in,
                              void* d_out, int out_size, void* d_ws, size_t ws_size,
                              hipStream_t stream) {
    const float* x      = (const float*)d_in[0];
    const int*   ei     = (const int*)d_in[1];
    const float* W1     = (const float*)d_in[2];
    const float* a_src1 = (const float*)d_in[3];
    const float* a_dst1 = (const float*)d_in[4];
    const float* b1     = (const float*)d_in[5];
    const float* W2     = (const float*)d_in[6];
    const float* a_src2 = (const float*)d_in[7];
    const float* a_dst2 = (const float*)d_in[8];
    const float* b2     = (const float*)d_in[9];
    float* out = (float*)d_out;

    const size_t NF = (size_t)Nn * F1;   // 5,120,000
    float* f = (float*)d_ws;
    float* tmp   = f;                    // NF floats (head partials, layer 2)
    float* as1   = tmp + NF;
    float* ad1   = as1 + Nn * NH;
    float* as2   = ad1 + Nn * NH;
    float* ad2   = as2 + Nn * NH;
    float* invd1 = ad2 + Nn * NH;
    float* invd2 = invd1 + Nn * NH;
    float2* epk  = (float2*)(invd2 + Nn * NH);       // NH*EE float2
    _Float16* hh   = (_Float16*)(epk + (size_t)NH * EE);  // NF halves
    _Float16* aggh = hh + NF;                             // NF halves
    _Float16* xh   = aggh + NF;                           // Nn*INF_ halves
    _Float16* w1t  = xh + (size_t)Nn * INF_;              // F1*INF_ halves
    _Float16* w2t  = w1t + (size_t)F1 * INF_;             // F2*F1 halves
    int* counts    = (int*)(w2t + (size_t)F2 * F1);
    int* offsets   = counts + Nn;
    int* cursor    = offsets + Nn + 1;
    int* csr       = cursor + Nn;
    int* blocksums = csr + EE;

    // CSR build
    init_counts<<<(Nn + 255) / 256, 256, 0, stream>>>(counts);
    count_edges<<<(Ee + 255) / 256, 256, 0, stream>>>(ei, counts);
    reduce_counts<<<NB, 256, 0, stream>>>(counts, blocksums);
    scan_sums<<<1, 64, 0, stream>>>(blocksums);
    scan_final<<<NB, 256, 0, stream>>>(counts, blocksums, offsets, cursor);
    scatter_edges<<<(EE + 255) / 256, 256, 0, stream>>>(ei, cursor, csr);

    // fp16 conversions
    conv_f16<<<(Nn * INF_ + 255) / 256, 256, 0, stream>>>(x, xh, Nn * INF_);
    transpose_f16<<<dim3(F1 / 64, INF_ / 4), 256, 0, stream>>>(W1, w1t, INF_, F1);
    transpose_f16<<<dim3(F2 / 64, F1 / 4), 256, 0, stream>>>(W2, w2t, F1, F2);

    // Layer 1: h = x @ W1 (MFMA fp16, fused alpha dots)
    mfma_gemm<<<dim3((Nn + 63) / 64, F1 / 128), 256, 0, stream>>>(
        xh, w1t, hh, a_src1, a_dst1, as1, ad1, Nn, INF_);
    passA<<<Nn / 16, 256, 0, stream>>>(offsets, csr, as1, ad1, epk, invd1);
    passB1h<<<(Nn / 4) * 8, 256, 0, stream>>>(offsets, epk, invd1, (const __half*)hh, b1, aggh);

    // Layer 2: h2 = agg @ W2 (MFMA fp16, fused alpha dots)
    mfma_gemm<<<dim3((Nn + 63) / 64, F2 / 128), 256, 0, stream>>>(
        aggh, w2t, hh, a_src2, a_dst2, as2, ad2, Nn, F1);
    passA<<<Nn / 16, 256, 0, stream>>>(offsets, csr, as2, ad2, epk, invd2);
    passB2h<<<(Nn / 4) * 8, 256, 0, stream>>>(offsets, epk, invd2, (const __half*)hh, tmp);
    reduce4<<<(Nn * OUTC + 255) / 256, 256, 0, stream>>>(tmp, b2, out);
}

// Round 8
// 261.945 us; speedup vs baseline: 1.9054x; 1.0219x over previous
//
#include <hip/hip_runtime.h>
#include <hip/hip_fp16.h>
#include <math.h>

#define Nn 10000
#define Ee 320000
#define EE 330000      // E + N self loops
#define EEPS 400064    // padded edge capacity per head (+64 sentinel)
#define INF_ 256
#define HID 128
#define OUTC 128
#define NH 4
#define F1 512         // NH*HID
#define F2 512         // NH*OUTC
#define SLOPE 0.2f
#define NB 40          // ceil(Nn/256)

static __device__ __forceinline__ float lrelu(float x) { return fmaxf(x, SLOPE * x); }

using frag_ab = __attribute__((ext_vector_type(8))) _Float16;  // 4 VGPRs
using frag_c  = __attribute__((ext_vector_type(4))) float;     // 4 VGPRs

// ---------------- CSR build ----------------
__global__ void init_counts(int* counts) {
    int i = blockIdx.x * 256 + threadIdx.x;
    if (i < Nn) counts[i] = 1;  // self loop
}

__global__ void count_edges(const int* __restrict__ ei, int* counts) {
    int e = blockIdx.x * 256 + threadIdx.x;
    if (e < Ee) atomicAdd(&counts[ei[Ee + e]], 1);
}

__global__ __launch_bounds__(256) void reduce_counts(const int* __restrict__ counts,
                                                     int* __restrict__ blocksums, int pad) {
    __shared__ int sd[256];
    int t = threadIdx.x, i = blockIdx.x * 256 + t;
    int v = (i < Nn) ? counts[i] : 0;
    if (pad) v = (v + 7) & ~7;
    sd[t] = v;
    __syncthreads();
    for (int off = 128; off > 0; off >>= 1) {
        if (t < off) sd[t] += sd[t + off];
        __syncthreads();
    }
    if (t == 0) blocksums[blockIdx.x] = sd[0];
}

__global__ __launch_bounds__(64) void scan_sums(int* blocksums) {
    int t = threadIdx.x;
    int orig = (t < NB) ? blocksums[t] : 0;
    int v = orig;
    for (int off = 1; off < 64; off <<= 1) {
        int u = __shfl_up(v, off);
        if (t >= off) v += u;
    }
    if (t < NB) blocksums[t] = v - orig;  // exclusive
}

__global__ __launch_bounds__(256) void scan_final(const int* __restrict__ counts,
                                                  const int* __restrict__ blocksums,
                                                  int* __restrict__ offsets,
                                                  int* __restrict__ cursor,
                                                  int pad) {
    __shared__ int sd[256];
    int t = threadIdx.x, i = blockIdx.x * 256 + t;
    int v = (i < Nn) ? counts[i] : 0;
    if (pad) v = (v + 7) & ~7;
    sd[t] = v;
    __syncthreads();
    int x = v;
    for (int off = 1; off < 256; off <<= 1) {
        int u = (t >= off) ? sd[t - off] : 0;
        __syncthreads();
        x += u;
        sd[t] = x;
        __syncthreads();
    }
    int base = blocksums[blockIdx.x];
    int e = base + x - v;  // exclusive
    if (i < Nn) {
        offsets[i] = e;
        if (cursor) cursor[i] = e;
        if (i == Nn - 1) offsets[Nn] = e + v;
    }
}

__global__ void init_sentinel(const int* __restrict__ poffsets, int2* __restrict__ epk) {
    int tp = poffsets[Nn];
    int i = threadIdx.x;  // 64
#pragma unroll
    for (int h = 0; h < NH; h++)
        epk[(size_t)h * EEPS + tp + i] = make_int2(0, 0);
}

__global__ void scatter_edges(const int* __restrict__ ei, int* cursor, int* __restrict__ csr) {
    int t = blockIdx.x * 256 + threadIdx.x;
    if (t >= EE) return;
    int src, dst;
    if (t < Ee) { src = ei[t]; dst = ei[Ee + t]; }
    else        { src = t - Ee; dst = t - Ee; }
    int pos = atomicAdd(&cursor[dst], 1);
    csr[pos] = src;
}

// ---------------- fp32 -> fp16 conversions ----------------
__global__ void conv_f16(const float* __restrict__ in, _Float16* __restrict__ out, int n) {
    int i = blockIdx.x * 256 + threadIdx.x;
    if (i < n) out[i] = (_Float16)in[i];
}

// W [K x N] fp32 -> WT [N x K] fp16
__global__ void transpose_f16(const float* __restrict__ W, _Float16* __restrict__ WT,
                              int K, int N) {
    int n = blockIdx.x * 64 + (threadIdx.x & 63);
    int k = blockIdx.y * 4 + (threadIdx.x >> 6);
    if (n < N && k < K) WT[(size_t)n * K + k] = (_Float16)W[(size_t)k * N + n];
}

// ---------------- MFMA fp16 GEMM + fused alpha dots ----------------
#define LDK 40
__global__ __launch_bounds__(256) void mfma_gemm(const _Float16* __restrict__ A,
                                                 const _Float16* __restrict__ BT,
                                                 _Float16* __restrict__ C,
                                                 const float* __restrict__ a_src,
                                                 const float* __restrict__ a_dst,
                                                 float* __restrict__ as_out,
                                                 float* __restrict__ ad_out,
                                                 int M, int K) {
    __shared__ _Float16 As[64 * LDK];
    __shared__ _Float16 Bs[128 * LDK];
    const int tid = threadIdx.x;
    const int wave = tid >> 6, lane = tid & 63;
    const int q = lane >> 4, ml = lane & 15;
    const int bm = blockIdx.x * 64, bn = blockIdx.y * 128;
    const int head = blockIdx.y;
    const int srow = tid >> 2, scol = (tid & 3) * 8;

    frag_c acc[8];
#pragma unroll
    for (int f = 0; f < 8; f++)
#pragma unroll
        for (int r = 0; r < 4; r++) acc[f][r] = 0.f;

    for (int k0 = 0; k0 < K; k0 += 32) {
        int gm = bm + srow;
        frag_ab av;
        if (gm < M) av = *(const frag_ab*)(A + (size_t)gm * K + k0 + scol);
        else {
#pragma unroll
            for (int j = 0; j < 8; j++) av[j] = (_Float16)0.f;
        }
        *(frag_ab*)&As[srow * LDK + scol] = av;
        *(frag_ab*)&Bs[srow * LDK + scol] =
            *(const frag_ab*)(BT + (size_t)(bn + srow) * K + k0 + scol);
        *(frag_ab*)&Bs[(64 + srow) * LDK + scol] =
            *(const frag_ab*)(BT + (size_t)(bn + 64 + srow) * K + k0 + scol);
        __syncthreads();
        frag_ab a = *(frag_ab*)&As[(wave * 16 + ml) * LDK + q * 8];
#pragma unroll
        for (int f = 0; f < 8; f++) {
            frag_ab b = *(frag_ab*)&Bs[(f * 16 + ml) * LDK + q * 8];
            acc[f] = __builtin_amdgcn_mfma_f32_16x16x32_f16(a, b, acc[f], 0, 0, 0);
        }
        __syncthreads();
    }
    float asum[4] = {}, dsum[4] = {};
#pragma unroll
    for (int f = 0; f < 8; f++) {
        int cl = f * 16 + ml;
        int col = bn + cl;
        float sa = a_src[head * 128 + cl];
        float da = a_dst[head * 128 + cl];
#pragma unroll
        for (int r = 0; r < 4; r++) {
            int row = bm + wave * 16 + q * 4 + r;
            if (row < M) C[(size_t)row * (NH * 128) + col] = (_Float16)acc[f][r];
            asum[r] += acc[f][r] * sa;
            dsum[r] += acc[f][r] * da;
        }
    }
#pragma unroll
    for (int r = 0; r < 4; r++) {
#pragma unroll
        for (int off = 1; off < 16; off <<= 1) {
            asum[r] += __shfl_xor(asum[r], off);
            dsum[r] += __shfl_xor(dsum[r], off);
        }
    }
    if (ml == 0) {
#pragma unroll
        for (int r = 0; r < 4; r++) {
            int row = bm + wave * 16 + q * 4 + r;
            if (row < M) {
                as_out[row * NH + head] = asum[r];
                ad_out[row * NH + head] = dsum[r];
            }
        }
    }
}

// ---------------- softmax pass A: quarter-wave per node, padded (src,w) output ----------------
__global__ __launch_bounds__(256) void passA(const int* __restrict__ offsets,
                                             const int* __restrict__ poffsets,
                                             const int* __restrict__ csr,
                                             const float* __restrict__ as,
                                             const float* __restrict__ ad,
                                             int2* __restrict__ epk,
                                             float* __restrict__ invd) {
    int n = blockIdx.x * 16 + (threadIdx.x >> 4);
    int l = threadIdx.x & 15;
    int start = offsets[n], end = offsets[n + 1];
    int pstart = poffsets[n], pend = poffsets[n + 1];
    int deg = end - start, pdeg = pend - pstart;
    float4 adv = *(const float4*)&ad[n * NH];
    float m0 = -1e30f, m1 = -1e30f, m2 = -1e30f, m3 = -1e30f;
    for (int idx = start + l; idx < end; idx += 16) {
        int src = csr[idx];
        float4 asv = *(const float4*)&as[src * NH];
        m0 = fmaxf(m0, lrelu(asv.x + adv.x));
        m1 = fmaxf(m1, lrelu(asv.y + adv.y));
        m2 = fmaxf(m2, lrelu(asv.z + adv.z));
        m3 = fmaxf(m3, lrelu(asv.w + adv.w));
    }
#pragma unroll
    for (int off = 8; off > 0; off >>= 1) {
        m0 = fmaxf(m0, __shfl_xor(m0, off));
        m1 = fmaxf(m1, __shfl_xor(m1, off));
        m2 = fmaxf(m2, __shfl_xor(m2, off));
        m3 = fmaxf(m3, __shfl_xor(m3, off));
    }
    float s0 = 0.f, s1 = 0.f, s2 = 0.f, s3 = 0.f;
    for (int k = l; k < pdeg; k += 16) {
        int src;
        float e0, e1, e2, e3;
        if (k < deg) {
            src = csr[start + k];
            float4 asv = *(const float4*)&as[src * NH];
            e0 = __expf(lrelu(asv.x + adv.x) - m0);
            e1 = __expf(lrelu(asv.y + adv.y) - m1);
            e2 = __expf(lrelu(asv.z + adv.z) - m2);
            e3 = __expf(lrelu(asv.w + adv.w) - m3);
        } else {
            src = n;
            e0 = e1 = e2 = e3 = 0.f;
        }
        int pos = pstart + k;
        epk[pos] = make_int2(src, __float_as_int(e0));
        epk[EEPS + pos] = make_int2(src, __float_as_int(e1));
        epk[2 * EEPS + pos] = make_int2(src, __float_as_int(e2));
        epk[3 * EEPS + pos] = make_int2(src, __float_as_int(e3));
        s0 += e0; s1 += e1; s2 += e2; s3 += e3;
    }
#pragma unroll
    for (int off = 8; off > 0; off >>= 1) {
        s0 += __shfl_xor(s0, off);
        s1 += __shfl_xor(s1, off);
        s2 += __shfl_xor(s2, off);
        s3 += __shfl_xor(s3, off);
    }
    if (l == 0) {
        *(float4*)&invd[n * NH] = make_float4(1.f / (s0 + 1e-16f), 1.f / (s1 + 1e-16f),
                                              1.f / (s2 + 1e-16f), 1.f / (s3 + 1e-16f));
    }
}

// ---------------- pass B layer 1: head-sliced, 8 edges x 16ch/lane, guard-free ----------------
// head = blockIdx&3 -> XCD pair; per-XCD slice = 10000*256B = 2.56 MB (L2-resident).
// lane: eg = lane>>3 (8 edges/iter), cg = lane&7 (8 lanes x 16 halves = 128 ch).
__global__ __launch_bounds__(256) void passB1n(const int* __restrict__ poffsets,
                                               const int2* __restrict__ epk,
                                               const float* __restrict__ invd,
                                               const _Float16* __restrict__ hh,
                                               const float* __restrict__ b1,
                                               _Float16* __restrict__ agg) {
    int head = blockIdx.x & 3;
    int n = (blockIdx.x >> 2) * 4 + (threadIdx.x >> 6);
    int lane = threadIdx.x & 63;
    int eg = lane >> 3, cg = lane & 7;
    int cbase = head * 128 + (cg << 4);
    int pstart = poffsets[n], pend = poffsets[n + 1];
    const int2* ep = epk + (size_t)head * EEPS;
    float acc[16] = {};
    int idx = pstart + eg;
    int2 p = ep[idx];  // pdeg >= 8 always
    while (idx < pend) {
        int nidx = idx + 8;
        int2 pn = ep[nidx];  // sentinel/next-node safe
        int src = p.x;
        float w = __int_as_float(p.y);
        const _Float16* hp = hh + (size_t)src * F1 + cbase;
        float4 r0 = *(const float4*)hp;
        float4 r1 = *(const float4*)(hp + 8);
        const _Float16* a0 = (const _Float16*)&r0;
        const _Float16* a1 = (const _Float16*)&r1;
#pragma unroll
        for (int j = 0; j < 8; j++) acc[j] = fmaf((float)a0[j], w, acc[j]);
#pragma unroll
        for (int j = 0; j < 8; j++) acc[8 + j] = fmaf((float)a1[j], w, acc[8 + j]);
        idx = nidx; p = pn;
    }
#pragma unroll
    for (int j = 0; j < 16; j++) {
        acc[j] += __shfl_xor(acc[j], 8);
        acc[j] += __shfl_xor(acc[j], 16);
        acc[j] += __shfl_xor(acc[j], 32);
    }
    if (eg == 0) {
        float inv = invd[n * NH + head];
        _Float16 oh[16];
#pragma unroll
        for (int j = 0; j < 16; j++)
            oh[j] = (_Float16)fmaxf(acc[j] * inv + b1[cbase + j], 0.f);
        *(float4*)&agg[(size_t)n * F1 + cbase] = *(float4*)oh;
        *(float4*)&agg[(size_t)n * F1 + cbase + 8] = *(float4*)(oh + 8);
    }
}

// ---------------- pass B layer 2: same layout -> tmp[head][n][128] ----------------
__global__ __launch_bounds__(256) void passB2n(const int* __restrict__ poffsets,
                                               const int2* __restrict__ epk,
                                               const float* __restrict__ invd,
                                               const _Float16* __restrict__ hh,
                                               float* __restrict__ tmp) {
    int head = blockIdx.x & 3;
    int n = (blockIdx.x >> 2) * 4 + (threadIdx.x >> 6);
    int lane = threadIdx.x & 63;
    int eg = lane >> 3, cg = lane & 7;
    int cbase = head * 128 + (cg << 4);
    int pstart = poffsets[n], pend = poffsets[n + 1];
    const int2* ep = epk + (size_t)head * EEPS;
    float acc[16] = {};
    int idx = pstart + eg;
    int2 p = ep[idx];
    while (idx < pend) {
        int nidx = idx + 8;
        int2 pn = ep[nidx];
        int src = p.x;
        float w = __int_as_float(p.y);
        const _Float16* hp = hh + (size_t)src * F2 + cbase;
        float4 r0 = *(const float4*)hp;
        float4 r1 = *(const float4*)(hp + 8);
        const _Float16* a0 = (const _Float16*)&r0;
        const _Float16* a1 = (const _Float16*)&r1;
#pragma unroll
        for (int j = 0; j < 8; j++) acc[j] = fmaf((float)a0[j], w, acc[j]);
#pragma unroll
        for (int j = 0; j < 8; j++) acc[8 + j] = fmaf((float)a1[j], w, acc[8 + j]);
        idx = nidx; p = pn;
    }
#pragma unroll
    for (int j = 0; j < 16; j++) {
        acc[j] += __shfl_xor(acc[j], 8);
        acc[j] += __shfl_xor(acc[j], 16);
        acc[j] += __shfl_xor(acc[j], 32);
    }
    if (eg == 0) {
        float q = 0.25f * invd[n * NH + head];
        float* tp = tmp + (size_t)head * Nn * 128 + (size_t)n * 128 + (cg << 4);
        float4 o0 = make_float4(acc[0] * q, acc[1] * q, acc[2] * q, acc[3] * q);
        float4 o1 = make_float4(acc[4] * q, acc[5] * q, acc[6] * q, acc[7] * q);
        float4 o2 = make_float4(acc[8] * q, acc[9] * q, acc[10] * q, acc[11] * q);
        float4 o3 = make_float4(acc[12] * q, acc[13] * q, acc[14] * q, acc[15] * q);
        *(float4*)tp = o0;
        *(float4*)(tp + 4) = o1;
        *(float4*)(tp + 8) = o2;
        *(float4*)(tp + 12) = o3;
    }
}

// ---------------- reduce 4 heads + bias -> d_out ----------------
__global__ void reduce4(const float* __restrict__ tmp, const float* __restrict__ b2,
                        float* __restrict__ out) {
    int i = blockIdx.x * 256 + threadIdx.x;
    if (i >= Nn * OUTC) return;
    int oc = i & 127;
    const size_t S = (size_t)Nn * 128;
    float v = tmp[i] + tmp[S + i] + tmp[2 * S + i] + tmp[3 * S + i];
    out[i] = v + b2[oc];
}

extern "C" void kernel_launch(void* const* d_in, const int* in_sizes, int n_in,
                              void* d_out, int out_size, void* d_ws, size_t ws_size,
                              hipStream_t stream) {
    const float* x      = (const float*)d_in[0];
    const int*   ei     = (const int*)d_in[1];
    const float* W1     = (const float*)d_in[2];
    const float* a_src1 = (const float*)d_in[3];
    const float* a_dst1 = (const float*)d_in[4];
    const float* b1     = (const float*)d_in[5];
    const float* W2     = (const float*)d_in[6];
    const float* a_src2 = (const float*)d_in[7];
    const float* a_dst2 = (const float*)d_in[8];
    const float* b2     = (const float*)d_in[9];
    float* out = (float*)d_out;

    const size_t NF = (size_t)Nn * F1;   // 5,120,000
    float* f = (float*)d_ws;
    float* tmp   = f;                    // NF floats
    float* as1   = tmp + NF;
    float* ad1   = as1 + Nn * NH;
    float* as2   = ad1 + Nn * NH;
    float* ad2   = as2 + Nn * NH;
    float* invd1 = ad2 + Nn * NH;
    float* invd2 = invd1 + Nn * NH;
    int2* epk    = (int2*)(invd2 + Nn * NH);        // NH*EEPS int2
    _Float16* hh   = (_Float16*)(epk + (size_t)NH * EEPS);
    _Float16* aggh = hh + NF;
    _Float16* xh   = aggh + NF;
    _Float16* w1t  = xh + (size_t)Nn * INF_;
    _Float16* w2t  = w1t + (size_t)F1 * INF_;
    int* counts     = (int*)(w2t + (size_t)F2 * F1);
    int* offsets    = counts + Nn;
    int* poffsets   = offsets + Nn + 1;
    int* cursor     = poffsets + Nn + 1;
    int* csr        = cursor + Nn;
    int* blocksums  = csr + EE;
    int* blocksums2 = blocksums + NB;

    // CSR build (unpadded offsets for csr, padded offsets for epk)
    init_counts<<<(Nn + 255) / 256, 256, 0, stream>>>(counts);
    count_edges<<<(Ee + 255) / 256, 256, 0, stream>>>(ei, counts);
    reduce_counts<<<NB, 256, 0, stream>>>(counts, blocksums, 0);
    scan_sums<<<1, 64, 0, stream>>>(blocksums);
    scan_final<<<NB, 256, 0, stream>>>(counts, blocksums, offsets, cursor, 0);
    scatter_edges<<<(EE + 255) / 256, 256, 0, stream>>>(ei, cursor, csr);
    reduce_counts<<<NB, 256, 0, stream>>>(counts, blocksums2, 1);
    scan_sums<<<1, 64, 0, stream>>>(blocksums2);
    scan_final<<<NB, 256, 0, stream>>>(counts, blocksums2, poffsets, (int*)nullptr, 1);
    init_sentinel<<<1, 64, 0, stream>>>(poffsets, epk);

    // fp16 conversions
    conv_f16<<<(Nn * INF_ + 255) / 256, 256, 0, stream>>>(x, xh, Nn * INF_);
    transpose_f16<<<dim3(F1 / 64, INF_ / 4), 256, 0, stream>>>(W1, w1t, INF_, F1);
    transpose_f16<<<dim3(F2 / 64, F1 / 4), 256, 0, stream>>>(W2, w2t, F1, F2);

    // Layer 1
    mfma_gemm<<<dim3((Nn + 63) / 64, F1 / 128), 256, 0, stream>>>(
        xh, w1t, hh, a_src1, a_dst1, as1, ad1, Nn, INF_);
    passA<<<Nn / 16, 256, 0, stream>>>(offsets, poffsets, csr, as1, ad1, epk, invd1);
    passB1n<<<(Nn / 4) * 4, 256, 0, stream>>>(poffsets, epk, invd1, hh, b1, aggh);

    // Layer 2
    mfma_gemm<<<dim3((Nn + 63) / 64, F2 / 128), 256, 0, stream>>>(
        aggh, w2t, hh, a_src2, a_dst2, as2, ad2, Nn, F1);
    passA<<<Nn / 16, 256, 0, stream>>>(offsets, poffsets, csr, as2, ad2, epk, invd2);
    passB2n<<<(Nn / 4) * 4, 256, 0, stream>>>(poffsets, epk, invd2, hh, tmp);
    reduce4<<<(Nn * OUTC + 255) / 256, 256, 0, stream>>>(tmp, b2, out);
}